// Round 1
// baseline (750.888 us; speedup 1.0000x reference)
//
#include <hip/hip_runtime.h>
#include <hip/hip_bf16.h>
#include <stdint.h>

// MoE top-2 of 8 experts.  B=2,T=1024 -> nt=2048 tokens, D=1024, H=4096, E=8.
// d_out layout: out[2*1024*1024] f32 | gate_value[2048*8] f32 | lb_loss[1] f32.

#define NTOK 2048
#define DDIM 1024
#define HDIM 4096
#define NEXP 8

typedef float  f32x4  __attribute__((ext_vector_type(4)));
typedef __bf16 bf16x8 __attribute__((ext_vector_type(8)));
typedef unsigned short u16x8 __attribute__((ext_vector_type(8)));

__device__ __forceinline__ unsigned short f2bf(float f) {
  union { float f; unsigned int u; } v; v.f = f;
  unsigned int u = v.u;
  return (unsigned short)((u + 0x7fffu + ((u >> 16) & 1u)) >> 16);  // RNE
}

// ---------------- init: zero the atomic counters ----------------
__global__ void init_kernel(int* ecount, int* fill, float* gsum, float* top1c, float* nreal) {
  int t = threadIdx.x;
  if (t < NEXP) { ecount[t] = 0; fill[t] = 0; gsum[t] = 0.f; top1c[t] = 0.f; }
  if (t == 0) nreal[0] = 0.f;
}

// ---------------- gate: logits, softmax, top2, lb pieces ----------------
__global__ __launch_bounds__(256)
void gate_kernel(const float* __restrict__ x, const unsigned char* __restrict__ pmask,
                 const float* __restrict__ Wg, float* __restrict__ gate_out,
                 int* __restrict__ tix, float* __restrict__ twt,
                 int* __restrict__ ecount, float* __restrict__ gsum,
                 float* __restrict__ top1c, float* __restrict__ nreal)
{
  int wave = threadIdx.x >> 6, lane = threadIdx.x & 63;
  int t = blockIdx.x * 4 + wave;   // one wave per token
  const f32x4* x4 = (const f32x4*)(x + (size_t)t * DDIM);
  const f32x4* w4 = (const f32x4*)Wg;
  float acc[NEXP];
#pragma unroll
  for (int e = 0; e < NEXP; ++e) acc[e] = 0.f;
#pragma unroll
  for (int i = 0; i < 4; ++i) {
    f32x4 xv = x4[i * 64 + lane];
#pragma unroll
    for (int e = 0; e < NEXP; ++e) {
      f32x4 wv = w4[e * 256 + i * 64 + lane];
      acc[e] += xv[0]*wv[0] + xv[1]*wv[1] + xv[2]*wv[2] + xv[3]*wv[3];
    }
  }
#pragma unroll
  for (int e = 0; e < NEXP; ++e) {
    float v = acc[e];
#pragma unroll
    for (int off = 32; off > 0; off >>= 1) v += __shfl_xor(v, off, 64);
    acc[e] = v;
  }
  if (lane == 0) {
    bool pm = pmask[t] != 0;
    float m = acc[0];
#pragma unroll
    for (int e = 1; e < NEXP; ++e) m = fmaxf(m, acc[e]);
    float g[NEXP]; float s = 0.f;
#pragma unroll
    for (int e = 0; e < NEXP; ++e) { g[e] = expf(acc[e] - m); s += g[e]; }
    float inv = 1.f / s;
#pragma unroll
    for (int e = 0; e < NEXP; ++e) g[e] *= inv;
    if (pm) {
#pragma unroll
      for (int e = 0; e < NEXP; ++e) g[e] = 0.f;
    }
    // top2: strict > keeps first index on ties (matches jax top_k)
    int i1 = 0;
#pragma unroll
    for (int e = 1; e < NEXP; ++e) if (g[e] > g[i1]) i1 = e;
    int i2 = -1;
#pragma unroll
    for (int e = 0; e < NEXP; ++e) if (e != i1 && (i2 < 0 || g[e] > g[i2])) i2 = e;
    float w1 = g[i1], w2 = g[i2], ss = w1 + w2;
    if (ss == 0.f) ss = 1.f;
    w1 /= ss; w2 /= ss;
#pragma unroll
    for (int e = 0; e < NEXP; ++e) {
      gate_out[(size_t)t * NEXP + e] = g[e];
      atomicAdd(&gsum[e], g[e]);
    }
    tix[2*t] = i1; tix[2*t+1] = i2;
    twt[2*t] = w1; twt[2*t+1] = w2;
    if (!pm) {
      atomicAdd(&top1c[i1], 1.f);
      atomicAdd(nreal, 1.f);
      atomicAdd(&ecount[i1], 1);
      atomicAdd(&ecount[i2], 1);
    }
  }
}

// ---------------- scan offsets + lb loss ----------------
__global__ void scan_lb_kernel(const int* ecount, int* offs, const float* gsum,
                               const float* top1c, const float* nreal, float* lb_out)
{
  if (threadIdx.x == 0) {
    int o = 0;
    for (int e = 0; e < NEXP; ++e) { offs[e] = o; o += ecount[e]; }
    float n = nreal[0]; if (n <= 0.f) n = 1.f;
    float lb = 0.f;
    for (int e = 0; e < NEXP; ++e) lb += (top1c[e] / n) * (gsum[e] / n);
    lb_out[0] = (float)NEXP * lb;
  }
}

// ---------------- compaction: per-expert token lists ----------------
__global__ __launch_bounds__(256)
void compact_kernel(const unsigned char* __restrict__ pmask, const int* __restrict__ tix,
                    const float* __restrict__ twt, const int* __restrict__ offs,
                    int* __restrict__ fill, int* __restrict__ tok_list,
                    float* __restrict__ wgt_list, int* __restrict__ slot_of)
{
  int t = blockIdx.x * 256 + threadIdx.x;
  if (t >= NTOK) return;
  bool pm = pmask[t] != 0;
#pragma unroll
  for (int j = 0; j < 2; ++j) {
    if (pm) { slot_of[2*t + j] = -1; continue; }
    int e = tix[2*t + j];
    int pos = offs[e] + atomicAdd(&fill[e], 1);
    tok_list[pos] = t;
    wgt_list[pos] = twt[2*t + j];
    slot_of[2*t + j] = pos;
  }
}

// ---------------- GEMM1: h[slot,:] = relu(x[tok]·W1[e]^T + b1[e]) (bf16 out) ----------------
// 128x128 tile, BK=64, 4 waves (2x2), 4x4 frags of mfma 16x16x32 bf16.
// LDS rows padded to 72 shorts (144B) -> b128 read/write at 8-cycle floor.
#define LDSP 72
__global__ __launch_bounds__(256)
void gemm1_kernel(const float* __restrict__ x, const float* __restrict__ W1,
                  const float* __restrict__ b1, const int* __restrict__ ecount,
                  const int* __restrict__ offs, const int* __restrict__ tok_list,
                  unsigned short* __restrict__ hbuf)
{
  const int NTILE = HDIM / 128;   // 32
  const int MTILE = NTOK / 128;   // 16
  int bid = blockIdx.x;
  int e = bid / (MTILE * NTILE);
  int rem = bid % (MTILE * NTILE);
  int mt = rem / NTILE, ntile = rem % NTILE;
  int cnt = ecount[e];
  if (mt * 128 >= cnt) return;
  int off = offs[e];

  __shared__ unsigned short At[128 * LDSP];
  __shared__ unsigned short Bt[128 * LDSP];

  int tid = threadIdx.x;
  int lane = tid & 63;
  int wm = (tid >> 6) >> 1, wn = (tid >> 6) & 1;

  int srow = tid >> 1;
  int scol = (tid & 1) * 32;
  int mrow = mt * 128 + srow;
  int tok = tok_list[off + ((mrow < cnt) ? mrow : 0)];
  const float* aptr = x + (size_t)tok * DDIM + scol;
  const float* bptr = W1 + (size_t)e * HDIM * DDIM + (size_t)(ntile * 128 + srow) * DDIM + scol;
  unsigned short* awr = &At[srow * LDSP + scol];
  unsigned short* bwr = &Bt[srow * LDSP + scol];

  f32x4 acc[4][4];
#pragma unroll
  for (int m = 0; m < 4; ++m)
#pragma unroll
    for (int n = 0; n < 4; ++n) acc[m][n] = (f32x4){0.f, 0.f, 0.f, 0.f};

  for (int k0 = 0; k0 < DDIM; k0 += 64) {
#pragma unroll
    for (int p = 0; p < 4; ++p) {
      f32x4 a0 = *(const f32x4*)(aptr + k0 + p * 8);
      f32x4 a1 = *(const f32x4*)(aptr + k0 + p * 8 + 4);
      f32x4 b0 = *(const f32x4*)(bptr + k0 + p * 8);
      f32x4 b1v = *(const f32x4*)(bptr + k0 + p * 8 + 4);
      u16x8 pa, pb;
#pragma unroll
      for (int q = 0; q < 4; ++q) {
        pa[q] = f2bf(a0[q]); pa[q + 4] = f2bf(a1[q]);
        pb[q] = f2bf(b0[q]); pb[q + 4] = f2bf(b1v[q]);
      }
      *(u16x8*)(awr + p * 8) = pa;
      *(u16x8*)(bwr + p * 8) = pb;
    }
    __syncthreads();
#pragma unroll
    for (int ks = 0; ks < 2; ++ks) {
      int koff = ks * 32 + (lane >> 4) * 8;
      bf16x8 af[4], bfr[4];
#pragma unroll
      for (int m = 0; m < 4; ++m) af[m] = *(const bf16x8*)&At[(wm*64 + m*16 + (lane & 15)) * LDSP + koff];
#pragma unroll
      for (int n = 0; n < 4; ++n) bfr[n] = *(const bf16x8*)&Bt[(wn*64 + n*16 + (lane & 15)) * LDSP + koff];
#pragma unroll
      for (int m = 0; m < 4; ++m)
#pragma unroll
        for (int n = 0; n < 4; ++n)
          acc[m][n] = __builtin_amdgcn_mfma_f32_16x16x32_bf16(af[m], bfr[n], acc[m][n], 0, 0, 0);
    }
    __syncthreads();
  }
  // epilogue: +bias, relu, bf16 store to hbuf
#pragma unroll
  for (int n = 0; n < 4; ++n) {
    int col = ntile * 128 + wn * 64 + n * 16 + (lane & 15);
    float bias = b1[e * HDIM + col];
#pragma unroll
    for (int m = 0; m < 4; ++m) {
#pragma unroll
      for (int j = 0; j < 4; ++j) {
        int mr = mt * 128 + wm * 64 + m * 16 + ((lane >> 4) << 2) + j;
        if (mr < cnt) {
          float v = fmaxf(acc[m][n][j] + bias, 0.f);
          hbuf[(size_t)(off + mr) * HDIM + col] = f2bf(v);
        }
      }
    }
  }
}

// ---------------- GEMM2: y[slot,:] = w_slot * (h[slot]·W2[e]^T + b2[e]) ----------------
__global__ __launch_bounds__(256)
void gemm2_kernel(const unsigned short* __restrict__ hbuf, const float* __restrict__ W2,
                  const float* __restrict__ b2, const int* __restrict__ ecount,
                  const int* __restrict__ offs, const float* __restrict__ wgt_list,
                  float* __restrict__ ybuf)
{
  const int NTILE = DDIM / 128;   // 8
  const int MTILE = NTOK / 128;   // 16
  int bid = blockIdx.x;
  int e = bid / (MTILE * NTILE);
  int rem = bid % (MTILE * NTILE);
  int mt = rem / NTILE, ntile = rem % NTILE;
  int cnt = ecount[e];
  if (mt * 128 >= cnt) return;
  int off = offs[e];

  __shared__ unsigned short At[128 * LDSP];
  __shared__ unsigned short Bt[128 * LDSP];

  int tid = threadIdx.x;
  int lane = tid & 63;
  int wm = (tid >> 6) >> 1, wn = (tid >> 6) & 1;

  // A (hbuf, bf16): chunk mapping, 4 rows/thread
  int arow0 = tid >> 3;            // 0..31 (+32*it)
  int achk = (tid & 7) * 8;
  // B (W2, f32->bf16): row/halfrow mapping
  int brow = tid >> 1;
  int bcol = (tid & 1) * 32;
  const float* bptr = W2 + (size_t)e * DDIM * HDIM + (size_t)(ntile * 128 + brow) * HDIM + bcol;
  unsigned short* bwr = &Bt[brow * LDSP + bcol];

  f32x4 acc[4][4];
#pragma unroll
  for (int m = 0; m < 4; ++m)
#pragma unroll
    for (int n = 0; n < 4; ++n) acc[m][n] = (f32x4){0.f, 0.f, 0.f, 0.f};

  for (int k0 = 0; k0 < HDIM; k0 += 64) {
#pragma unroll
    for (int it = 0; it < 4; ++it) {
      int r = arow0 + it * 32;
      size_t slot = (size_t)(off + mt * 128 + r);    // hbuf padded, OOB-safe
      u16x8 v = *(const u16x8*)(hbuf + slot * HDIM + k0 + achk);
      *(u16x8*)&At[r * LDSP + achk] = v;
    }
#pragma unroll
    for (int p = 0; p < 4; ++p) {
      f32x4 b0 = *(const f32x4*)(bptr + k0 + p * 8);
      f32x4 b1v = *(const f32x4*)(bptr + k0 + p * 8 + 4);
      u16x8 pb;
#pragma unroll
      for (int q = 0; q < 4; ++q) { pb[q] = f2bf(b0[q]); pb[q + 4] = f2bf(b1v[q]); }
      *(u16x8*)(bwr + p * 8) = pb;
    }
    __syncthreads();
#pragma unroll
    for (int ks = 0; ks < 2; ++ks) {
      int koff = ks * 32 + (lane >> 4) * 8;
      bf16x8 af[4], bfr[4];
#pragma unroll
      for (int m = 0; m < 4; ++m) af[m] = *(const bf16x8*)&At[(wm*64 + m*16 + (lane & 15)) * LDSP + koff];
#pragma unroll
      for (int n = 0; n < 4; ++n) bfr[n] = *(const bf16x8*)&Bt[(wn*64 + n*16 + (lane & 15)) * LDSP + koff];
#pragma unroll
      for (int m = 0; m < 4; ++m)
#pragma unroll
        for (int n = 0; n < 4; ++n)
          acc[m][n] = __builtin_amdgcn_mfma_f32_16x16x32_bf16(af[m], bfr[n], acc[m][n], 0, 0, 0);
    }
    __syncthreads();
  }
  // epilogue: +bias, * gate weight, f32 store to ybuf
#pragma unroll
  for (int m = 0; m < 4; ++m) {
#pragma unroll
    for (int j = 0; j < 4; ++j) {
      int mr = mt * 128 + wm * 64 + m * 16 + ((lane >> 4) << 2) + j;
      if (mr >= cnt) continue;
      int slot = off + mr;
      float w = wgt_list[slot];
#pragma unroll
      for (int n = 0; n < 4; ++n) {
        int col = ntile * 128 + wn * 64 + n * 16 + (lane & 15);
        float y = acc[m][n][j] + b2[e * DDIM + col];
        ybuf[(size_t)slot * DDIM + col] = w * y;
      }
    }
  }
}

// ---------------- combine: out[t] = y[slotA] + y[slotB] ----------------
__global__ __launch_bounds__(256)
void combine_kernel(const float* __restrict__ ybuf, const int* __restrict__ slot_of,
                    float* __restrict__ out)
{
  int t = blockIdx.x;
  int d4 = threadIdx.x;
  int sA = slot_of[2*t], sB = slot_of[2*t + 1];
  f32x4 r = (f32x4){0.f, 0.f, 0.f, 0.f};
  if (sA >= 0) r += ((const f32x4*)(ybuf + (size_t)sA * DDIM))[d4];
  if (sB >= 0) r += ((const f32x4*)(ybuf + (size_t)sB * DDIM))[d4];
  ((f32x4*)(out + (size_t)t * DDIM))[d4] = r;
}

extern "C" void kernel_launch(void* const* d_in, const int* in_sizes, int n_in,
                              void* d_out, int out_size, void* d_ws, size_t ws_size,
                              hipStream_t stream)
{
  const float* x  = (const float*)d_in[0];
  const unsigned char* pm = (const unsigned char*)d_in[1];
  const float* Wg = (const float*)d_in[2];
  const float* W1 = (const float*)d_in[3];
  const float* b1 = (const float*)d_in[4];
  const float* W2 = (const float*)d_in[5];
  const float* b2 = (const float*)d_in[6];
  float* out = (float*)d_out;
  float* gate_out = out + (size_t)NTOK * DDIM;        // 2097152
  float* lb_out = gate_out + (size_t)NTOK * NEXP;     // 2113536

  char* w = (char*)d_ws;
  int*   ecount   = (int*)(w + 0);
  int*   offs     = (int*)(w + 64);
  int*   fill     = (int*)(w + 128);
  float* gsum     = (float*)(w + 192);
  float* top1c    = (float*)(w + 256);
  float* nreal    = (float*)(w + 320);
  int*   tix      = (int*)(w + 512);
  float* twt      = (float*)(w + 512 + 16384);
  int*   tok_list = (int*)(w + 512 + 32768);
  float* wgt_list = (float*)(w + 512 + 32768 + 17408);
  int*   slot_of  = (int*)(w + 512 + 32768 + 17408 + 16384);
  uintptr_t ph = ((uintptr_t)(w + 512 + 32768 + 17408 + 16384 + 16384) + 255) & ~(uintptr_t)255;
  unsigned short* hbuf = (unsigned short*)ph;                       // (4096+128) x 4096 bf16
  float* ybuf = (float*)(ph + (size_t)(2 * NTOK + 128) * HDIM * 2); // 4096 x 1024 f32

  init_kernel<<<1, 64, 0, stream>>>(ecount, fill, gsum, top1c, nreal);
  gate_kernel<<<NTOK / 4, 256, 0, stream>>>(x, pm, Wg, gate_out, tix, twt, ecount, gsum, top1c, nreal);
  scan_lb_kernel<<<1, 64, 0, stream>>>(ecount, offs, gsum, top1c, nreal, lb_out);
  compact_kernel<<<NTOK / 256, 256, 0, stream>>>(pm, tix, twt, offs, fill, tok_list, wgt_list, slot_of);
  gemm1_kernel<<<NEXP * (NTOK / 128) * (HDIM / 128), 256, 0, stream>>>(x, W1, b1, ecount, offs, tok_list, hbuf);
  gemm2_kernel<<<NEXP * (NTOK / 128) * (DDIM / 128), 256, 0, stream>>>(hbuf, W2, b2, ecount, offs, wgt_list, ybuf);
  combine_kernel<<<NTOK, 256, 0, stream>>>(ybuf, slot_of, out);
}

// Round 2
// 624.451 us; speedup vs baseline: 1.2025x; 1.2025x over previous
//
#include <hip/hip_runtime.h>
#include <hip/hip_bf16.h>
#include <stdint.h>

// MoE top-2 of 8 experts.  B=2,T=1024 -> nt=2048 tokens, D=1024, H=4096, E=8.
// d_out layout: out[2*1024*1024] f32 | gate_value[2048*8] f32 | lb_loss[1] f32.

#define NTOK 2048
#define DDIM 1024
#define HDIM 4096
#define NEXP 8
#define KSPLIT 4

typedef float  f32x4  __attribute__((ext_vector_type(4)));
typedef __bf16 bf16x8 __attribute__((ext_vector_type(8)));
typedef unsigned short u16x8 __attribute__((ext_vector_type(8)));

// ---------------- init: zero the atomic counters ----------------
__global__ void init_kernel(int* ecount, int* fill, float* gsum, float* top1c, float* nreal) {
  int t = threadIdx.x;
  if (t < NEXP) { ecount[t] = 0; fill[t] = 0; gsum[t] = 0.f; top1c[t] = 0.f; }
  if (t == 0) nreal[0] = 0.f;
}

// ---------------- zero ybuf (gemm2 accumulates with atomics) ----------------
__global__ __launch_bounds__(256)
void zero_y_kernel(float* __restrict__ y) {
  size_t i = (size_t)blockIdx.x * 256 + threadIdx.x;
  ((f32x4*)y)[i] = (f32x4){0.f, 0.f, 0.f, 0.f};
}

// ---------------- gate: logits, softmax, top2, lb pieces ----------------
__global__ __launch_bounds__(256)
void gate_kernel(const float* __restrict__ x, const unsigned char* __restrict__ pmask,
                 const float* __restrict__ Wg, float* __restrict__ gate_out,
                 int* __restrict__ tix, float* __restrict__ twt,
                 int* __restrict__ ecount, float* __restrict__ gsum,
                 float* __restrict__ top1c, float* __restrict__ nreal)
{
  int wave = threadIdx.x >> 6, lane = threadIdx.x & 63;
  int t = blockIdx.x * 4 + wave;   // one wave per token
  const f32x4* x4 = (const f32x4*)(x + (size_t)t * DDIM);
  const f32x4* w4 = (const f32x4*)Wg;
  float acc[NEXP];
#pragma unroll
  for (int e = 0; e < NEXP; ++e) acc[e] = 0.f;
#pragma unroll
  for (int i = 0; i < 4; ++i) {
    f32x4 xv = x4[i * 64 + lane];
#pragma unroll
    for (int e = 0; e < NEXP; ++e) {
      f32x4 wv = w4[e * 256 + i * 64 + lane];
      acc[e] += xv[0]*wv[0] + xv[1]*wv[1] + xv[2]*wv[2] + xv[3]*wv[3];
    }
  }
#pragma unroll
  for (int e = 0; e < NEXP; ++e) {
    float v = acc[e];
#pragma unroll
    for (int off = 32; off > 0; off >>= 1) v += __shfl_xor(v, off, 64);
    acc[e] = v;
  }
  if (lane == 0) {
    bool pm = pmask[t] != 0;
    float m = acc[0];
#pragma unroll
    for (int e = 1; e < NEXP; ++e) m = fmaxf(m, acc[e]);
    float g[NEXP]; float s = 0.f;
#pragma unroll
    for (int e = 0; e < NEXP; ++e) { g[e] = expf(acc[e] - m); s += g[e]; }
    float inv = 1.f / s;
#pragma unroll
    for (int e = 0; e < NEXP; ++e) g[e] *= inv;
    if (pm) {
#pragma unroll
      for (int e = 0; e < NEXP; ++e) g[e] = 0.f;
    }
    // top2: strict > keeps first index on ties (matches jax top_k)
    int i1 = 0;
#pragma unroll
    for (int e = 1; e < NEXP; ++e) if (g[e] > g[i1]) i1 = e;
    int i2 = -1;
#pragma unroll
    for (int e = 0; e < NEXP; ++e) if (e != i1 && (i2 < 0 || g[e] > g[i2])) i2 = e;
    float w1 = g[i1], w2 = g[i2], ss = w1 + w2;
    if (ss == 0.f) ss = 1.f;
    w1 /= ss; w2 /= ss;
#pragma unroll
    for (int e = 0; e < NEXP; ++e) {
      gate_out[(size_t)t * NEXP + e] = g[e];
      atomicAdd(&gsum[e], g[e]);
    }
    tix[2*t] = i1; tix[2*t+1] = i2;
    twt[2*t] = w1; twt[2*t+1] = w2;
    if (!pm) {
      atomicAdd(&top1c[i1], 1.f);
      atomicAdd(nreal, 1.f);
      atomicAdd(&ecount[i1], 1);
      atomicAdd(&ecount[i2], 1);
    }
  }
}

// ---------------- scan offsets + lb loss ----------------
__global__ void scan_lb_kernel(const int* ecount, int* offs, const float* gsum,
                               const float* top1c, const float* nreal, float* lb_out)
{
  if (threadIdx.x == 0) {
    int o = 0;
    for (int e = 0; e < NEXP; ++e) { offs[e] = o; o += ecount[e]; }
    float n = nreal[0]; if (n <= 0.f) n = 1.f;
    float lb = 0.f;
    for (int e = 0; e < NEXP; ++e) lb += (top1c[e] / n) * (gsum[e] / n);
    lb_out[0] = (float)NEXP * lb;
  }
}

// ---------------- compaction: per-expert token lists ----------------
__global__ __launch_bounds__(256)
void compact_kernel(const unsigned char* __restrict__ pmask, const int* __restrict__ tix,
                    const float* __restrict__ twt, const int* __restrict__ offs,
                    int* __restrict__ fill, int* __restrict__ tok_list,
                    float* __restrict__ wgt_list, int* __restrict__ slot_of)
{
  int t = blockIdx.x * 256 + threadIdx.x;
  if (t >= NTOK) return;
  bool pm = pmask[t] != 0;
#pragma unroll
  for (int j = 0; j < 2; ++j) {
    if (pm) { slot_of[2*t + j] = -1; continue; }
    int e = tix[2*t + j];
    int pos = offs[e] + atomicAdd(&fill[e], 1);
    tok_list[pos] = t;
    wgt_list[pos] = twt[2*t + j];
    slot_of[2*t + j] = pos;
  }
}

// ---------------- GEMM1: h[slot,:] = relu(x[tok]·W1[e]^T + b1[e]) (bf16 out) ----------------
// 128x128 tile, BK=64, 4 waves (2x2), 4x4 frags of mfma 16x16x32 bf16.
// LDS rows padded to 72 shorts (144B).  f32->bf16 via HW cvt (scalar casts ->
// compiler fuses to v_cvt_pk_bf16_f32), not manual bit-twiddle (m240).
#define LDSP 72
__global__ __launch_bounds__(256)
void gemm1_kernel(const float* __restrict__ x, const float* __restrict__ W1,
                  const float* __restrict__ b1, const int* __restrict__ ecount,
                  const int* __restrict__ offs, const int* __restrict__ tok_list,
                  unsigned short* __restrict__ hbuf)
{
  const int NTILE = HDIM / 128;   // 32
  const int MTILE = NTOK / 128;   // 16
  int bid = blockIdx.x;
  int e = bid / (MTILE * NTILE);
  int rem = bid % (MTILE * NTILE);
  int mt = rem / NTILE, ntile = rem % NTILE;
  int cnt = ecount[e];
  if (mt * 128 >= cnt) return;
  int off = offs[e];

  __shared__ unsigned short At[128 * LDSP];
  __shared__ unsigned short Bt[128 * LDSP];

  int tid = threadIdx.x;
  int lane = tid & 63;
  int wm = (tid >> 6) >> 1, wn = (tid >> 6) & 1;

  int srow = tid >> 1;
  int scol = (tid & 1) * 32;
  int mrow = mt * 128 + srow;
  int tok = tok_list[off + ((mrow < cnt) ? mrow : 0)];
  const float* aptr = x + (size_t)tok * DDIM + scol;
  const float* bptr = W1 + (size_t)e * HDIM * DDIM + (size_t)(ntile * 128 + srow) * DDIM + scol;
  unsigned short* awr = &At[srow * LDSP + scol];
  unsigned short* bwr = &Bt[srow * LDSP + scol];

  f32x4 acc[4][4];
#pragma unroll
  for (int m = 0; m < 4; ++m)
#pragma unroll
    for (int n = 0; n < 4; ++n) acc[m][n] = (f32x4){0.f, 0.f, 0.f, 0.f};

  for (int k0 = 0; k0 < DDIM; k0 += 64) {
#pragma unroll
    for (int p = 0; p < 4; ++p) {
      f32x4 a0 = *(const f32x4*)(aptr + k0 + p * 8);
      f32x4 a1 = *(const f32x4*)(aptr + k0 + p * 8 + 4);
      f32x4 b0 = *(const f32x4*)(bptr + k0 + p * 8);
      f32x4 b1v = *(const f32x4*)(bptr + k0 + p * 8 + 4);
      bf16x8 pa, pb;
#pragma unroll
      for (int q = 0; q < 4; ++q) {
        pa[q] = (__bf16)a0[q]; pa[q + 4] = (__bf16)a1[q];
        pb[q] = (__bf16)b0[q]; pb[q + 4] = (__bf16)b1v[q];
      }
      *(bf16x8*)(awr + p * 8) = pa;
      *(bf16x8*)(bwr + p * 8) = pb;
    }
    __syncthreads();
#pragma unroll
    for (int ks = 0; ks < 2; ++ks) {
      int koff = ks * 32 + (lane >> 4) * 8;
      bf16x8 af[4], bfr[4];
#pragma unroll
      for (int m = 0; m < 4; ++m) af[m] = *(const bf16x8*)&At[(wm*64 + m*16 + (lane & 15)) * LDSP + koff];
#pragma unroll
      for (int n = 0; n < 4; ++n) bfr[n] = *(const bf16x8*)&Bt[(wn*64 + n*16 + (lane & 15)) * LDSP + koff];
#pragma unroll
      for (int m = 0; m < 4; ++m)
#pragma unroll
        for (int n = 0; n < 4; ++n)
          acc[m][n] = __builtin_amdgcn_mfma_f32_16x16x32_bf16(af[m], bfr[n], acc[m][n], 0, 0, 0);
    }
    __syncthreads();
  }
  // epilogue: +bias, relu, bf16 store to hbuf
#pragma unroll
  for (int n = 0; n < 4; ++n) {
    int col = ntile * 128 + wn * 64 + n * 16 + (lane & 15);
    float bias = b1[e * HDIM + col];
#pragma unroll
    for (int m = 0; m < 4; ++m) {
#pragma unroll
      for (int j = 0; j < 4; ++j) {
        int mr = mt * 128 + wm * 64 + m * 16 + ((lane >> 4) << 2) + j;
        if (mr < cnt) {
          float v = fmaxf(acc[m][n][j] + bias, 0.f);
          ((__bf16*)hbuf)[(size_t)(off + mr) * HDIM + col] = (__bf16)v;
        }
      }
    }
  }
}

// ---------------- GEMM2 (K-split): partial y[slot,:] += h[slot]·W2[e]^T ----------------
// K=4096 split into KSPLIT chunks of 1024 -> 4x the active blocks (occupancy
// was the round-1 bottleneck: 9%).  Raw partials atomicAdd'ed into zeroed
// ybuf; bias + gate weight applied in combine.
__global__ __launch_bounds__(256)
void gemm2_kernel(const unsigned short* __restrict__ hbuf, const float* __restrict__ W2,
                  const int* __restrict__ ecount, const int* __restrict__ offs,
                  float* __restrict__ ybuf)
{
  const int NTILE = DDIM / 128;   // 8
  const int MTILE = NTOK / 128;   // 16
  int bid = blockIdx.x;
  int e = bid / (MTILE * NTILE * KSPLIT);
  int rem = bid % (MTILE * NTILE * KSPLIT);
  int mt = rem / (NTILE * KSPLIT);
  int rem2 = rem % (NTILE * KSPLIT);
  int ntile = rem2 / KSPLIT, kc = rem2 % KSPLIT;
  int cnt = ecount[e];
  if (mt * 128 >= cnt) return;
  int off = offs[e];

  __shared__ unsigned short At[128 * LDSP];
  __shared__ unsigned short Bt[128 * LDSP];

  int tid = threadIdx.x;
  int lane = tid & 63;
  int wm = (tid >> 6) >> 1, wn = (tid >> 6) & 1;

  // A (hbuf, bf16): chunk mapping, 4 rows/thread
  int arow0 = tid >> 3;            // 0..31 (+32*it)
  int achk = (tid & 7) * 8;
  // B (W2, f32->bf16): row/halfrow mapping
  int brow = tid >> 1;
  int bcol = (tid & 1) * 32;
  const float* bptr = W2 + (size_t)e * DDIM * HDIM + (size_t)(ntile * 128 + brow) * HDIM + bcol;
  unsigned short* bwr = &Bt[brow * LDSP + bcol];

  f32x4 acc[4][4];
#pragma unroll
  for (int m = 0; m < 4; ++m)
#pragma unroll
    for (int n = 0; n < 4; ++n) acc[m][n] = (f32x4){0.f, 0.f, 0.f, 0.f};

  int kbeg = kc * (HDIM / KSPLIT);
  int kend = kbeg + (HDIM / KSPLIT);
  for (int k0 = kbeg; k0 < kend; k0 += 64) {
#pragma unroll
    for (int it = 0; it < 4; ++it) {
      int r = arow0 + it * 32;
      size_t slot = (size_t)(off + mt * 128 + r);    // hbuf padded, OOB-safe
      u16x8 v = *(const u16x8*)(hbuf + slot * HDIM + k0 + achk);
      *(u16x8*)&At[r * LDSP + achk] = v;
    }
#pragma unroll
    for (int p = 0; p < 4; ++p) {
      f32x4 b0 = *(const f32x4*)(bptr + k0 + p * 8);
      f32x4 b1v = *(const f32x4*)(bptr + k0 + p * 8 + 4);
      bf16x8 pb;
#pragma unroll
      for (int q = 0; q < 4; ++q) { pb[q] = (__bf16)b0[q]; pb[q + 4] = (__bf16)b1v[q]; }
      *(bf16x8*)(bwr + p * 8) = pb;
    }
    __syncthreads();
#pragma unroll
    for (int ks = 0; ks < 2; ++ks) {
      int koff = ks * 32 + (lane >> 4) * 8;
      bf16x8 af[4], bfr[4];
#pragma unroll
      for (int m = 0; m < 4; ++m) af[m] = *(const bf16x8*)&At[(wm*64 + m*16 + (lane & 15)) * LDSP + koff];
#pragma unroll
      for (int n = 0; n < 4; ++n) bfr[n] = *(const bf16x8*)&Bt[(wn*64 + n*16 + (lane & 15)) * LDSP + koff];
#pragma unroll
      for (int m = 0; m < 4; ++m)
#pragma unroll
        for (int n = 0; n < 4; ++n)
          acc[m][n] = __builtin_amdgcn_mfma_f32_16x16x32_bf16(af[m], bfr[n], acc[m][n], 0, 0, 0);
    }
    __syncthreads();
  }
  // epilogue: atomic accumulate raw partials (bias+weight applied in combine)
#pragma unroll
  for (int m = 0; m < 4; ++m) {
#pragma unroll
    for (int j = 0; j < 4; ++j) {
      int mr = mt * 128 + wm * 64 + m * 16 + ((lane >> 4) << 2) + j;
      if (mr >= cnt) continue;
      int slot = off + mr;
#pragma unroll
      for (int n = 0; n < 4; ++n) {
        int col = ntile * 128 + wn * 64 + n * 16 + (lane & 15);
        atomicAdd(&ybuf[(size_t)slot * DDIM + col], acc[m][n][j]);
      }
    }
  }
}

// ---------------- combine: out[t] = wA*(y[sA]+b2[eA]) + wB*(y[sB]+b2[eB]) ----------------
__global__ __launch_bounds__(256)
void combine_kernel(const float* __restrict__ ybuf, const int* __restrict__ slot_of,
                    const int* __restrict__ tix, const float* __restrict__ twt,
                    const float* __restrict__ b2, float* __restrict__ out)
{
  int t = blockIdx.x;
  int d4 = threadIdx.x;
  int sA = slot_of[2*t], sB = slot_of[2*t + 1];
  f32x4 r = (f32x4){0.f, 0.f, 0.f, 0.f};
  if (sA >= 0) {
    float wA = twt[2*t];
    f32x4 y = ((const f32x4*)(ybuf + (size_t)sA * DDIM))[d4];
    f32x4 b = ((const f32x4*)(b2 + (size_t)tix[2*t] * DDIM))[d4];
    r += wA * (y + b);
  }
  if (sB >= 0) {
    float wB = twt[2*t + 1];
    f32x4 y = ((const f32x4*)(ybuf + (size_t)sB * DDIM))[d4];
    f32x4 b = ((const f32x4*)(b2 + (size_t)tix[2*t + 1] * DDIM))[d4];
    r += wB * (y + b);
  }
  ((f32x4*)(out + (size_t)t * DDIM))[d4] = r;
}

extern "C" void kernel_launch(void* const* d_in, const int* in_sizes, int n_in,
                              void* d_out, int out_size, void* d_ws, size_t ws_size,
                              hipStream_t stream)
{
  const float* x  = (const float*)d_in[0];
  const unsigned char* pm = (const unsigned char*)d_in[1];
  const float* Wg = (const float*)d_in[2];
  const float* W1 = (const float*)d_in[3];
  const float* b1 = (const float*)d_in[4];
  const float* W2 = (const float*)d_in[5];
  const float* b2 = (const float*)d_in[6];
  float* out = (float*)d_out;
  float* gate_out = out + (size_t)NTOK * DDIM;        // 2097152
  float* lb_out = gate_out + (size_t)NTOK * NEXP;     // 2113536

  char* w = (char*)d_ws;
  int*   ecount   = (int*)(w + 0);
  int*   offs     = (int*)(w + 64);
  int*   fill     = (int*)(w + 128);
  float* gsum     = (float*)(w + 192);
  float* top1c    = (float*)(w + 256);
  float* nreal    = (float*)(w + 320);
  int*   tix      = (int*)(w + 512);
  float* twt      = (float*)(w + 512 + 16384);
  int*   tok_list = (int*)(w + 512 + 32768);
  float* wgt_list = (float*)(w + 512 + 32768 + 17408);
  int*   slot_of  = (int*)(w + 512 + 32768 + 17408 + 16384);
  uintptr_t ph = ((uintptr_t)(w + 512 + 32768 + 17408 + 16384 + 16384) + 255) & ~(uintptr_t)255;
  unsigned short* hbuf = (unsigned short*)ph;                       // (4096+128) x 4096 bf16
  float* ybuf = (float*)(ph + (size_t)(2 * NTOK + 128) * HDIM * 2); // 4096 x 1024 f32

  init_kernel<<<1, 64, 0, stream>>>(ecount, fill, gsum, top1c, nreal);
  zero_y_kernel<<<(2 * NTOK * DDIM / 4) / 256, 256, 0, stream>>>(ybuf);
  gate_kernel<<<NTOK / 4, 256, 0, stream>>>(x, pm, Wg, gate_out, tix, twt, ecount, gsum, top1c, nreal);
  scan_lb_kernel<<<1, 64, 0, stream>>>(ecount, offs, gsum, top1c, nreal, lb_out);
  compact_kernel<<<NTOK / 256, 256, 0, stream>>>(pm, tix, twt, offs, fill, tok_list, wgt_list, slot_of);
  gemm1_kernel<<<NEXP * (NTOK / 128) * (HDIM / 128), 256, 0, stream>>>(x, W1, b1, ecount, offs, tok_list, hbuf);
  gemm2_kernel<<<NEXP * (NTOK / 128) * (DDIM / 128) * KSPLIT, 256, 0, stream>>>(hbuf, W2, ecount, offs, ybuf);
  combine_kernel<<<NTOK, 256, 0, stream>>>(ybuf, slot_of, tix, twt, b2, out);
}

// Round 3
// 511.098 us; speedup vs baseline: 1.4692x; 1.2218x over previous
//
#include <hip/hip_runtime.h>
#include <hip/hip_bf16.h>
#include <stdint.h>

// MoE top-2 of 8 experts.  B=2,T=1024 -> nt=2048 tokens, D=1024, H=4096, E=8.
// d_out layout: out[2*1024*1024] f32 | gate_value[2048*8] f32 | lb_loss[1] f32.
//
// R3 structure: pre-convert weights to bf16, then m97-style GEMMs
// (128x128 tile, BK=64, linear LDS, global_load_lds dwordx4 staging,
// 2-barrier loop).  No LDS swizzle: T2 is null on 2-phase structures.

#define NTOK 2048
#define DDIM 1024
#define HDIM 4096
#define NEXP 8
#define KSPLIT 4

typedef float  f32x4  __attribute__((ext_vector_type(4)));
typedef __bf16 bf16x8 __attribute__((ext_vector_type(8)));
typedef __bf16 bf16x4 __attribute__((ext_vector_type(4)));

typedef const __attribute__((address_space(1))) void g1_t;
typedef __attribute__((address_space(3))) void l3_t;
__device__ __forceinline__ void gld16(const void* g, void* l) {
  // async global->LDS, 16B/lane; LDS dest = wave-uniform base + lane*16
  __builtin_amdgcn_global_load_lds((g1_t*)g, (l3_t*)l, 16, 0, 0);
}

// ---------------- init: zero the atomic counters ----------------
__global__ void init_kernel(int* ecount, int* fill, float* gsum, float* top1c, float* nreal) {
  int t = threadIdx.x;
  if (t < NEXP) { ecount[t] = 0; fill[t] = 0; gsum[t] = 0.f; top1c[t] = 0.f; }
  if (t == 0) nreal[0] = 0.f;
}

// ---------------- f32 -> bf16 bulk convert (grid-stride, 8 elems/thread) ----------------
__global__ __launch_bounds__(256)
void conv_kernel(const float* __restrict__ src, __bf16* __restrict__ dst, long n8) {
  long i = (long)blockIdx.x * 256 + threadIdx.x;
  long stride = (long)gridDim.x * 256;
  for (; i < n8; i += stride) {
    f32x4 a = ((const f32x4*)src)[2 * i];
    f32x4 b = ((const f32x4*)src)[2 * i + 1];
    bf16x8 o;
#pragma unroll
    for (int q = 0; q < 4; ++q) { o[q] = (__bf16)a[q]; o[q + 4] = (__bf16)b[q]; }
    ((bf16x8*)dst)[i] = o;
  }
}

// ---------------- zero ybuf (gemm2 accumulates with atomics) ----------------
__global__ __launch_bounds__(256)
void zero_y_kernel(float* __restrict__ y) {
  size_t i = (size_t)blockIdx.x * 256 + threadIdx.x;
  ((f32x4*)y)[i] = (f32x4){0.f, 0.f, 0.f, 0.f};
}

// ---------------- gate: logits, softmax, top2, lb pieces; also emits xbf ----------------
__global__ __launch_bounds__(256)
void gate_kernel(const float* __restrict__ x, const unsigned char* __restrict__ pmask,
                 const float* __restrict__ Wg, float* __restrict__ gate_out,
                 int* __restrict__ tix, float* __restrict__ twt,
                 int* __restrict__ ecount, float* __restrict__ gsum,
                 float* __restrict__ top1c, float* __restrict__ nreal,
                 __bf16* __restrict__ xbf)
{
  int wave = threadIdx.x >> 6, lane = threadIdx.x & 63;
  int t = blockIdx.x * 4 + wave;   // one wave per token
  const f32x4* x4 = (const f32x4*)(x + (size_t)t * DDIM);
  const f32x4* w4 = (const f32x4*)Wg;
  bf16x4* xb4 = (bf16x4*)(xbf + (size_t)t * DDIM);
  float acc[NEXP];
#pragma unroll
  for (int e = 0; e < NEXP; ++e) acc[e] = 0.f;
#pragma unroll
  for (int i = 0; i < 4; ++i) {
    f32x4 xv = x4[i * 64 + lane];
    bf16x4 xo;
#pragma unroll
    for (int q = 0; q < 4; ++q) xo[q] = (__bf16)xv[q];
    xb4[i * 64 + lane] = xo;
#pragma unroll
    for (int e = 0; e < NEXP; ++e) {
      f32x4 wv = w4[e * 256 + i * 64 + lane];
      acc[e] += xv[0]*wv[0] + xv[1]*wv[1] + xv[2]*wv[2] + xv[3]*wv[3];
    }
  }
#pragma unroll
  for (int e = 0; e < NEXP; ++e) {
    float v = acc[e];
#pragma unroll
    for (int off = 32; off > 0; off >>= 1) v += __shfl_xor(v, off, 64);
    acc[e] = v;
  }
  if (lane == 0) {
    bool pm = pmask[t] != 0;
    float m = acc[0];
#pragma unroll
    for (int e = 1; e < NEXP; ++e) m = fmaxf(m, acc[e]);
    float g[NEXP]; float s = 0.f;
#pragma unroll
    for (int e = 0; e < NEXP; ++e) { g[e] = expf(acc[e] - m); s += g[e]; }
    float inv = 1.f / s;
#pragma unroll
    for (int e = 0; e < NEXP; ++e) g[e] *= inv;
    if (pm) {
#pragma unroll
      for (int e = 0; e < NEXP; ++e) g[e] = 0.f;
    }
    int i1 = 0;
#pragma unroll
    for (int e = 1; e < NEXP; ++e) if (g[e] > g[i1]) i1 = e;
    int i2 = -1;
#pragma unroll
    for (int e = 0; e < NEXP; ++e) if (e != i1 && (i2 < 0 || g[e] > g[i2])) i2 = e;
    float w1 = g[i1], w2 = g[i2], ss = w1 + w2;
    if (ss == 0.f) ss = 1.f;
    w1 /= ss; w2 /= ss;
#pragma unroll
    for (int e = 0; e < NEXP; ++e) {
      gate_out[(size_t)t * NEXP + e] = g[e];
      atomicAdd(&gsum[e], g[e]);
    }
    tix[2*t] = i1; tix[2*t+1] = i2;
    twt[2*t] = w1; twt[2*t+1] = w2;
    if (!pm) {
      atomicAdd(&top1c[i1], 1.f);
      atomicAdd(nreal, 1.f);
      atomicAdd(&ecount[i1], 1);
      atomicAdd(&ecount[i2], 1);
    }
  }
}

// ---------------- scan offsets + lb loss ----------------
__global__ void scan_lb_kernel(const int* ecount, int* offs, const float* gsum,
                               const float* top1c, const float* nreal, float* lb_out)
{
  if (threadIdx.x == 0) {
    int o = 0;
    for (int e = 0; e < NEXP; ++e) { offs[e] = o; o += ecount[e]; }
    float n = nreal[0]; if (n <= 0.f) n = 1.f;
    float lb = 0.f;
    for (int e = 0; e < NEXP; ++e) lb += (top1c[e] / n) * (gsum[e] / n);
    lb_out[0] = (float)NEXP * lb;
  }
}

// ---------------- compaction: per-expert token lists ----------------
__global__ __launch_bounds__(256)
void compact_kernel(const unsigned char* __restrict__ pmask, const int* __restrict__ tix,
                    const int* __restrict__ offs, int* __restrict__ fill,
                    int* __restrict__ tok_list, int* __restrict__ slot_of)
{
  int t = blockIdx.x * 256 + threadIdx.x;
  if (t >= NTOK) return;
  bool pm = pmask[t] != 0;
#pragma unroll
  for (int j = 0; j < 2; ++j) {
    if (pm) { slot_of[2*t + j] = -1; continue; }
    int e = tix[2*t + j];
    int pos = offs[e] + atomicAdd(&fill[e], 1);
    tok_list[pos] = t;
    slot_of[2*t + j] = pos;
  }
}

// ---------------- GEMM1: h[slot,:] = relu(xbf[tok]·W1bf[e]^T + b1[e]) ----------------
// m97 structure: 128x128 tile, BK=64, linear LDS [128][64] bf16,
// global_load_lds dwordx4 staging, 2 barriers per K-step.
__global__ __launch_bounds__(256)
void gemm1_kernel(const __bf16* __restrict__ xbf, const __bf16* __restrict__ w1bf,
                  const float* __restrict__ b1, const int* __restrict__ ecount,
                  const int* __restrict__ offs, const int* __restrict__ tok_list,
                  __bf16* __restrict__ hbuf)
{
  const int NTILE = HDIM / 128;   // 32
  const int MTILE = NTOK / 128;   // 16
  int bid = blockIdx.x;
  int e = bid / (MTILE * NTILE);
  int rem = bid % (MTILE * NTILE);
  int mt = rem / NTILE, nt = rem % NTILE;
  int cnt = ecount[e];
  if (mt * 128 >= cnt) return;
  int off = offs[e];

  __shared__ __bf16 At[128 * 64];
  __shared__ __bf16 Bt[128 * 64];

  int tid = threadIdx.x, lane = tid & 63, wave = tid >> 6;
  int wm = wave >> 1, wn = wave & 1;

  // staging: round r (0..3): lane stages 16B of row r*32 + wave*8 + (lane>>3), chunk lane&7
  const __bf16* aP[4];
  const __bf16* bP[4];
#pragma unroll
  for (int r = 0; r < 4; ++r) {
    int row = r * 32 + wave * 8 + (lane >> 3);
    int mrow = mt * 128 + row;
    int tok = tok_list[off + ((mrow < cnt) ? mrow : 0)];
    aP[r] = xbf + (size_t)tok * DDIM + (lane & 7) * 8;
    bP[r] = w1bf + (size_t)e * HDIM * DDIM + (size_t)(nt * 128 + row) * DDIM + (lane & 7) * 8;
  }
  __bf16* lA = At + wave * 512;   // wave-uniform LDS base; +r*2048 per round
  __bf16* lB = Bt + wave * 512;

  f32x4 acc[4][4];
#pragma unroll
  for (int m = 0; m < 4; ++m)
#pragma unroll
    for (int n = 0; n < 4; ++n) acc[m][n] = (f32x4){0.f, 0.f, 0.f, 0.f};

  for (int k0 = 0; k0 < DDIM; k0 += 64) {
#pragma unroll
    for (int r = 0; r < 4; ++r) {
      gld16(aP[r] + k0, lA + r * 2048);
      gld16(bP[r] + k0, lB + r * 2048);
    }
    __syncthreads();   // drains vmcnt -> tiles ready
#pragma unroll
    for (int ks = 0; ks < 2; ++ks) {
      int koff = ks * 32 + (lane >> 4) * 8;
      bf16x8 af[4], bfr[4];
#pragma unroll
      for (int m = 0; m < 4; ++m) af[m] = *(const bf16x8*)&At[(wm*64 + m*16 + (lane & 15)) * 64 + koff];
#pragma unroll
      for (int n = 0; n < 4; ++n) bfr[n] = *(const bf16x8*)&Bt[(wn*64 + n*16 + (lane & 15)) * 64 + koff];
#pragma unroll
      for (int m = 0; m < 4; ++m)
#pragma unroll
        for (int n = 0; n < 4; ++n)
          acc[m][n] = __builtin_amdgcn_mfma_f32_16x16x32_bf16(af[m], bfr[n], acc[m][n], 0, 0, 0);
    }
    __syncthreads();   // protect LDS before next stage
  }
  // epilogue: +bias, relu, bf16 store
#pragma unroll
  for (int n = 0; n < 4; ++n) {
    int col = nt * 128 + wn * 64 + n * 16 + (lane & 15);
    float bias = b1[e * HDIM + col];
#pragma unroll
    for (int m = 0; m < 4; ++m) {
#pragma unroll
      for (int j = 0; j < 4; ++j) {
        int mr = mt * 128 + wm * 64 + m * 16 + ((lane >> 4) << 2) + j;
        if (mr < cnt) {
          float v = fmaxf(acc[m][n][j] + bias, 0.f);
          hbuf[(size_t)(off + mr) * HDIM + col] = (__bf16)v;
        }
      }
    }
  }
}

// ---------------- GEMM2 (K-split): ybuf[slot,:] += hbuf[slot]·W2bf[e]^T ----------------
__global__ __launch_bounds__(256)
void gemm2_kernel(const __bf16* __restrict__ hbuf, const __bf16* __restrict__ w2bf,
                  const int* __restrict__ ecount, const int* __restrict__ offs,
                  float* __restrict__ ybuf)
{
  const int NTILE = DDIM / 128;   // 8
  const int MTILE = NTOK / 128;   // 16
  int bid = blockIdx.x;
  int e = bid / (MTILE * NTILE * KSPLIT);
  int rem = bid % (MTILE * NTILE * KSPLIT);
  int mt = rem / (NTILE * KSPLIT);
  int rem2 = rem % (NTILE * KSPLIT);
  int nt = rem2 / KSPLIT, kc = rem2 % KSPLIT;
  int cnt = ecount[e];
  if (mt * 128 >= cnt) return;
  int off = offs[e];

  __shared__ __bf16 At[128 * 64];
  __shared__ __bf16 Bt[128 * 64];

  int tid = threadIdx.x, lane = tid & 63, wave = tid >> 6;
  int wm = wave >> 1, wn = wave & 1;

  const __bf16* aP[4];
  const __bf16* bP[4];
#pragma unroll
  for (int r = 0; r < 4; ++r) {
    int row = r * 32 + wave * 8 + (lane >> 3);
    // hbuf rows are contiguous compacted slots; padded rows hold benign junk
    aP[r] = hbuf + (size_t)(off + mt * 128 + row) * HDIM + (lane & 7) * 8;
    bP[r] = w2bf + (size_t)e * DDIM * HDIM + (size_t)(nt * 128 + row) * HDIM + (lane & 7) * 8;
  }
  __bf16* lA = At + wave * 512;
  __bf16* lB = Bt + wave * 512;

  f32x4 acc[4][4];
#pragma unroll
  for (int m = 0; m < 4; ++m)
#pragma unroll
    for (int n = 0; n < 4; ++n) acc[m][n] = (f32x4){0.f, 0.f, 0.f, 0.f};

  int kbeg = kc * (HDIM / KSPLIT);
  int kend = kbeg + (HDIM / KSPLIT);
  for (int k0 = kbeg; k0 < kend; k0 += 64) {
#pragma unroll
    for (int r = 0; r < 4; ++r) {
      gld16(aP[r] + k0, lA + r * 2048);
      gld16(bP[r] + k0, lB + r * 2048);
    }
    __syncthreads();
#pragma unroll
    for (int ks = 0; ks < 2; ++ks) {
      int koff = ks * 32 + (lane >> 4) * 8;
      bf16x8 af[4], bfr[4];
#pragma unroll
      for (int m = 0; m < 4; ++m) af[m] = *(const bf16x8*)&At[(wm*64 + m*16 + (lane & 15)) * 64 + koff];
#pragma unroll
      for (int n = 0; n < 4; ++n) bfr[n] = *(const bf16x8*)&Bt[(wn*64 + n*16 + (lane & 15)) * 64 + koff];
#pragma unroll
      for (int m = 0; m < 4; ++m)
#pragma unroll
        for (int n = 0; n < 4; ++n)
          acc[m][n] = __builtin_amdgcn_mfma_f32_16x16x32_bf16(af[m], bfr[n], acc[m][n], 0, 0, 0);
    }
    __syncthreads();
  }
  // epilogue: atomic accumulate raw partials (bias+gate weight in combine)
#pragma unroll
  for (int m = 0; m < 4; ++m) {
#pragma unroll
    for (int j = 0; j < 4; ++j) {
      int mr = mt * 128 + wm * 64 + m * 16 + ((lane >> 4) << 2) + j;
      if (mr >= cnt) continue;
      int slot = off + mr;
#pragma unroll
      for (int n = 0; n < 4; ++n) {
        int col = nt * 128 + wn * 64 + n * 16 + (lane & 15);
        atomicAdd(&ybuf[(size_t)slot * DDIM + col], acc[m][n][j]);
      }
    }
  }
}

// ---------------- combine: out[t] = wA*(y[sA]+b2[eA]) + wB*(y[sB]+b2[eB]) ----------------
__global__ __launch_bounds__(256)
void combine_kernel(const float* __restrict__ ybuf, const int* __restrict__ slot_of,
                    const int* __restrict__ tix, const float* __restrict__ twt,
                    const float* __restrict__ b2, float* __restrict__ out)
{
  int t = blockIdx.x;
  int d4 = threadIdx.x;
  int sA = slot_of[2*t], sB = slot_of[2*t + 1];
  f32x4 r = (f32x4){0.f, 0.f, 0.f, 0.f};
  if (sA >= 0) {
    float wA = twt[2*t];
    f32x4 y = ((const f32x4*)(ybuf + (size_t)sA * DDIM))[d4];
    f32x4 b = ((const f32x4*)(b2 + (size_t)tix[2*t] * DDIM))[d4];
    r += wA * (y + b);
  }
  if (sB >= 0) {
    float wB = twt[2*t + 1];
    f32x4 y = ((const f32x4*)(ybuf + (size_t)sB * DDIM))[d4];
    f32x4 b = ((const f32x4*)(b2 + (size_t)tix[2*t + 1] * DDIM))[d4];
    r += wB * (y + b);
  }
  ((f32x4*)(out + (size_t)t * DDIM))[d4] = r;
}

extern "C" void kernel_launch(void* const* d_in, const int* in_sizes, int n_in,
                              void* d_out, int out_size, void* d_ws, size_t ws_size,
                              hipStream_t stream)
{
  const float* x  = (const float*)d_in[0];
  const unsigned char* pm = (const unsigned char*)d_in[1];
  const float* Wg = (const float*)d_in[2];
  const float* W1 = (const float*)d_in[3];
  const float* b1 = (const float*)d_in[4];
  const float* W2 = (const float*)d_in[5];
  const float* b2 = (const float*)d_in[6];
  float* out = (float*)d_out;
  float* gate_out = out + (size_t)NTOK * DDIM;        // 2097152
  float* lb_out = gate_out + (size_t)NTOK * NEXP;     // 2113536

  char* w = (char*)d_ws;
  int*   ecount   = (int*)(w + 0);
  int*   offs     = (int*)(w + 64);
  int*   fill     = (int*)(w + 128);
  float* gsum     = (float*)(w + 192);
  float* top1c    = (float*)(w + 256);
  float* nreal    = (float*)(w + 320);
  int*   tix      = (int*)(w + 512);                       // 16 KB
  float* twt      = (float*)(w + 512 + 16384);             // 16 KB
  int*   tok_list = (int*)(w + 512 + 32768);               // 16 KB
  int*   slot_of  = (int*)(w + 512 + 49152);               // 16 KB
  uintptr_t p = ((uintptr_t)(w + 512 + 65536) + 255) & ~(uintptr_t)255;
  __bf16* xbf  = (__bf16*)p;                                    // 4 MB
  p += (size_t)NTOK * DDIM * 2;
  __bf16* wbf  = (__bf16*)p;                                    // 64 MB (W1bf, then W2bf)
  p += (size_t)NEXP * HDIM * DDIM * 2;
  __bf16* hbuf = (__bf16*)p;                                    // 33 MB
  p += (size_t)(2 * NTOK + 128) * HDIM * 2;
  float*  ybuf = (float*)p;                                     // 16 MB

  init_kernel<<<1, 64, 0, stream>>>(ecount, fill, gsum, top1c, nreal);
  conv_kernel<<<2048, 256, 0, stream>>>(W1, wbf, (long)NEXP * HDIM * DDIM / 8);
  zero_y_kernel<<<(2 * NTOK * DDIM / 4) / 256, 256, 0, stream>>>(ybuf);
  gate_kernel<<<NTOK / 4, 256, 0, stream>>>(x, pm, Wg, gate_out, tix, twt, ecount, gsum, top1c, nreal, xbf);
  scan_lb_kernel<<<1, 64, 0, stream>>>(ecount, offs, gsum, top1c, nreal, lb_out);
  compact_kernel<<<NTOK / 256, 256, 0, stream>>>(pm, tix, offs, fill, tok_list, slot_of);
  gemm1_kernel<<<NEXP * (NTOK / 128) * (HDIM / 128), 256, 0, stream>>>(xbf, wbf, b1, ecount, offs, tok_list, hbuf);
  conv_kernel<<<2048, 256, 0, stream>>>(W2, wbf, (long)NEXP * DDIM * HDIM / 8);
  gemm2_kernel<<<NEXP * (NTOK / 128) * (DDIM / 128) * KSPLIT, 256, 0, stream>>>(hbuf, wbf, ecount, offs, ybuf);
  combine_kernel<<<NTOK, 256, 0, stream>>>(ybuf, slot_of, tix, twt, b2, out);
}

// Round 4
// 300.633 us; speedup vs baseline: 2.4977x; 1.7001x over previous
//
#include <hip/hip_runtime.h>
#include <hip/hip_bf16.h>
#include <stdint.h>

// MoE top-2 of 8 experts.  B=2,T=1024 -> nt=2048 tokens, D=1024, H=4096, E=8.
// d_out layout: out[2*1024*1024] f32 | gate_value[2048*8] f32 | lb_loss[1] f32.
//
// R4: gate atomics removed (were ~225us of same-cacheline device atomics);
// stats via single-block tree reduction; ballot-aggregated compaction.
// GEMMs: m97 structure (128x128 tile, BK=64, linear LDS, global_load_lds).

#define NTOK 2048
#define DDIM 1024
#define HDIM 4096
#define NEXP 8
#define KSPLIT 4

typedef float  f32x4  __attribute__((ext_vector_type(4)));
typedef __bf16 bf16x8 __attribute__((ext_vector_type(8)));
typedef __bf16 bf16x4 __attribute__((ext_vector_type(4)));

typedef const __attribute__((address_space(1))) void g1_t;
typedef __attribute__((address_space(3))) void l3_t;
__device__ __forceinline__ void gld16(const void* g, void* l) {
  // async global->LDS, 16B/lane; LDS dest = wave-uniform base + lane*16
  __builtin_amdgcn_global_load_lds((g1_t*)g, (l3_t*)l, 16, 0, 0);
}

// ---------------- init: zero the fill counters ----------------
__global__ void init_kernel(int* fill) {
  int t = threadIdx.x;
  if (t < NEXP) fill[t] = 0;
}

// ---------------- f32 -> bf16 bulk convert (grid-stride, 8 elems/thread) ----------------
__global__ __launch_bounds__(256)
void conv_kernel(const float* __restrict__ src, __bf16* __restrict__ dst, long n8) {
  long i = (long)blockIdx.x * 256 + threadIdx.x;
  long stride = (long)gridDim.x * 256;
  for (; i < n8; i += stride) {
    f32x4 a = ((const f32x4*)src)[2 * i];
    f32x4 b = ((const f32x4*)src)[2 * i + 1];
    bf16x8 o;
#pragma unroll
    for (int q = 0; q < 4; ++q) { o[q] = (__bf16)a[q]; o[q + 4] = (__bf16)b[q]; }
    ((bf16x8*)dst)[i] = o;
  }
}

// ---------------- zero ybuf (gemm2 accumulates with atomics) ----------------
__global__ __launch_bounds__(256)
void zero_y_kernel(float* __restrict__ y) {
  size_t i = (size_t)blockIdx.x * 256 + threadIdx.x;
  ((f32x4*)y)[i] = (f32x4){0.f, 0.f, 0.f, 0.f};
}

// ---------------- gate: logits, softmax, top2; emits xbf.  NO atomics. ----------------
__global__ __launch_bounds__(256)
void gate_kernel(const float* __restrict__ x, const unsigned char* __restrict__ pmask,
                 const float* __restrict__ Wg, float* __restrict__ gate_out,
                 int* __restrict__ tix, float* __restrict__ twt,
                 __bf16* __restrict__ xbf)
{
  int wave = threadIdx.x >> 6, lane = threadIdx.x & 63;
  int t = blockIdx.x * 4 + wave;   // one wave per token
  const f32x4* x4 = (const f32x4*)(x + (size_t)t * DDIM);
  const f32x4* w4 = (const f32x4*)Wg;
  bf16x4* xb4 = (bf16x4*)(xbf + (size_t)t * DDIM);
  float acc[NEXP];
#pragma unroll
  for (int e = 0; e < NEXP; ++e) acc[e] = 0.f;
#pragma unroll
  for (int i = 0; i < 4; ++i) {
    f32x4 xv = x4[i * 64 + lane];
    bf16x4 xo;
#pragma unroll
    for (int q = 0; q < 4; ++q) xo[q] = (__bf16)xv[q];
    xb4[i * 64 + lane] = xo;
#pragma unroll
    for (int e = 0; e < NEXP; ++e) {
      f32x4 wv = w4[e * 256 + i * 64 + lane];
      acc[e] += xv[0]*wv[0] + xv[1]*wv[1] + xv[2]*wv[2] + xv[3]*wv[3];
    }
  }
#pragma unroll
  for (int e = 0; e < NEXP; ++e) {
    float v = acc[e];
#pragma unroll
    for (int off = 32; off > 0; off >>= 1) v += __shfl_xor(v, off, 64);
    acc[e] = v;
  }
  if (lane == 0) {
    bool pm = pmask[t] != 0;
    float m = acc[0];
#pragma unroll
    for (int e = 1; e < NEXP; ++e) m = fmaxf(m, acc[e]);
    float g[NEXP]; float s = 0.f;
#pragma unroll
    for (int e = 0; e < NEXP; ++e) { g[e] = expf(acc[e] - m); s += g[e]; }
    float inv = 1.f / s;
#pragma unroll
    for (int e = 0; e < NEXP; ++e) g[e] *= inv;
    if (pm) {
#pragma unroll
      for (int e = 0; e < NEXP; ++e) g[e] = 0.f;
    }
    int i1 = 0;
#pragma unroll
    for (int e = 1; e < NEXP; ++e) if (g[e] > g[i1]) i1 = e;
    int i2 = -1;
#pragma unroll
    for (int e = 0; e < NEXP; ++e) if (e != i1 && (i2 < 0 || g[e] > g[i2])) i2 = e;
    float w1 = g[i1], w2 = g[i2], ss = w1 + w2;
    if (ss == 0.f) ss = 1.f;
    w1 /= ss; w2 /= ss;
#pragma unroll
    for (int e = 0; e < NEXP; ++e) gate_out[(size_t)t * NEXP + e] = g[e];
    tix[2*t] = i1; tix[2*t+1] = i2;
    twt[2*t] = w1; twt[2*t+1] = w2;
  }
}

// ---------------- stats: single-block tree reduce -> ecount/offs/lb ----------------
__global__ __launch_bounds__(1024)
void stats_kernel(const float* __restrict__ gate_out, const int* __restrict__ tix,
                  const unsigned char* __restrict__ pmask,
                  int* __restrict__ ecount, int* __restrict__ offs,
                  float* __restrict__ lb_out)
{
  int tid = threadIdx.x, lane = tid & 63, wv = tid >> 6;   // 16 waves
  float lg[NEXP]; float lt1[NEXP]; int lec[NEXP]; float ln = 0.f;
#pragma unroll
  for (int e = 0; e < NEXP; ++e) { lg[e] = 0.f; lt1[e] = 0.f; lec[e] = 0; }
#pragma unroll
  for (int it = 0; it < NTOK / 1024; ++it) {
    int t = tid + it * 1024;
    f32x4 g0 = ((const f32x4*)(gate_out + (size_t)t * NEXP))[0];
    f32x4 g1 = ((const f32x4*)(gate_out + (size_t)t * NEXP))[1];
    lg[0] += g0[0]; lg[1] += g0[1]; lg[2] += g0[2]; lg[3] += g0[3];
    lg[4] += g1[0]; lg[5] += g1[1]; lg[6] += g1[2]; lg[7] += g1[3];
    if (!pmask[t]) {
      int i1 = tix[2*t], i2 = tix[2*t+1];
      lt1[i1] += 1.f; lec[i1] += 1; lec[i2] += 1; ln += 1.f;
    }
  }
  // wave-level reduce
#pragma unroll
  for (int e = 0; e < NEXP; ++e) {
#pragma unroll
    for (int off = 32; off > 0; off >>= 1) {
      lg[e]  += __shfl_xor(lg[e],  off, 64);
      lt1[e] += __shfl_xor(lt1[e], off, 64);
      lec[e] += __shfl_xor(lec[e], off, 64);
    }
  }
#pragma unroll
  for (int off = 32; off > 0; off >>= 1) ln += __shfl_xor(ln, off, 64);
  __shared__ float sg[16][NEXP], st[16][NEXP], sn[16];
  __shared__ int   se[16][NEXP];
  if (lane == 0) {
#pragma unroll
    for (int e = 0; e < NEXP; ++e) { sg[wv][e] = lg[e]; st[wv][e] = lt1[e]; se[wv][e] = lec[e]; }
    sn[wv] = ln;
  }
  __syncthreads();
  if (tid == 0) {
    float G[NEXP] = {0}, T1[NEXP] = {0}; int EC[NEXP] = {0}; float N = 0.f;
    for (int w = 0; w < 16; ++w) {
      N += sn[w];
#pragma unroll
      for (int e = 0; e < NEXP; ++e) { G[e] += sg[w][e]; T1[e] += st[w][e]; EC[e] += se[w][e]; }
    }
    int o = 0;
    for (int e = 0; e < NEXP; ++e) { ecount[e] = EC[e]; offs[e] = o; o += EC[e]; }
    if (N <= 0.f) N = 1.f;
    float lb = 0.f;
    for (int e = 0; e < NEXP; ++e) lb += (T1[e] / N) * (G[e] / N);
    lb_out[0] = (float)NEXP * lb;
  }
}

// ---------------- compaction: ballot-aggregated (1 atomic/wave/expert) ----------------
__global__ __launch_bounds__(256)
void compact_kernel(const unsigned char* __restrict__ pmask, const int* __restrict__ tix,
                    const int* __restrict__ offs, int* __restrict__ fill,
                    int* __restrict__ tok_list, int* __restrict__ slot_of)
{
  int t = blockIdx.x * 256 + threadIdx.x;
  int lane = threadIdx.x & 63;
  bool pm = pmask[t] != 0;
#pragma unroll
  for (int j = 0; j < 2; ++j) {
    int e = pm ? -1 : tix[2*t + j];
    int pos = -1;
#pragma unroll
    for (int ex = 0; ex < NEXP; ++ex) {
      unsigned long long mask = __ballot(e == ex);
      if (mask) {
        int leader = (int)(__ffsll((long long)mask) - 1);
        int base = 0;
        if (lane == leader) base = atomicAdd(&fill[ex], (int)__popcll(mask));
        base = __shfl(base, leader, 64);
        if (e == ex)
          pos = offs[ex] + base + (int)__popcll(mask & ((1ull << lane) - 1ull));
      }
    }
    if (e >= 0) { tok_list[pos] = t; slot_of[2*t + j] = pos; }
    else slot_of[2*t + j] = -1;
  }
}

// ---------------- GEMM1: h[slot,:] = relu(xbf[tok]·W1bf[e]^T + b1[e]) ----------------
// m97 structure: 128x128 tile, BK=64, linear LDS [128][64] bf16,
// global_load_lds dwordx4 staging, 2 barriers per K-step.
__global__ __launch_bounds__(256)
void gemm1_kernel(const __bf16* __restrict__ xbf, const __bf16* __restrict__ w1bf,
                  const float* __restrict__ b1, const int* __restrict__ ecount,
                  const int* __restrict__ offs, const int* __restrict__ tok_list,
                  __bf16* __restrict__ hbuf)
{
  const int NTILE = HDIM / 128;   // 32
  const int MTILE = NTOK / 128;   // 16
  int bid = blockIdx.x;
  int e = bid / (MTILE * NTILE);
  int rem = bid % (MTILE * NTILE);
  int mt = rem / NTILE, nt = rem % NTILE;
  int cnt = ecount[e];
  if (mt * 128 >= cnt) return;
  int off = offs[e];

  __shared__ __bf16 At[128 * 64];
  __shared__ __bf16 Bt[128 * 64];

  int tid = threadIdx.x, lane = tid & 63, wave = tid >> 6;
  int wm = wave >> 1, wn = wave & 1;

  const __bf16* aP[4];
  const __bf16* bP[4];
#pragma unroll
  for (int r = 0; r < 4; ++r) {
    int row = r * 32 + wave * 8 + (lane >> 3);
    int mrow = mt * 128 + row;
    int tok = tok_list[off + ((mrow < cnt) ? mrow : 0)];
    aP[r] = xbf + (size_t)tok * DDIM + (lane & 7) * 8;
    bP[r] = w1bf + (size_t)e * HDIM * DDIM + (size_t)(nt * 128 + row) * DDIM + (lane & 7) * 8;
  }
  __bf16* lA = At + wave * 512;   // wave-uniform LDS base; +r*2048 per round
  __bf16* lB = Bt + wave * 512;

  f32x4 acc[4][4];
#pragma unroll
  for (int m = 0; m < 4; ++m)
#pragma unroll
    for (int n = 0; n < 4; ++n) acc[m][n] = (f32x4){0.f, 0.f, 0.f, 0.f};

  for (int k0 = 0; k0 < DDIM; k0 += 64) {
#pragma unroll
    for (int r = 0; r < 4; ++r) {
      gld16(aP[r] + k0, lA + r * 2048);
      gld16(bP[r] + k0, lB + r * 2048);
    }
    __syncthreads();   // drains vmcnt -> tiles ready
#pragma unroll
    for (int ks = 0; ks < 2; ++ks) {
      int koff = ks * 32 + (lane >> 4) * 8;
      bf16x8 af[4], bfr[4];
#pragma unroll
      for (int m = 0; m < 4; ++m) af[m] = *(const bf16x8*)&At[(wm*64 + m*16 + (lane & 15)) * 64 + koff];
#pragma unroll
      for (int n = 0; n < 4; ++n) bfr[n] = *(const bf16x8*)&Bt[(wn*64 + n*16 + (lane & 15)) * 64 + koff];
#pragma unroll
      for (int m = 0; m < 4; ++m)
#pragma unroll
        for (int n = 0; n < 4; ++n)
          acc[m][n] = __builtin_amdgcn_mfma_f32_16x16x32_bf16(af[m], bfr[n], acc[m][n], 0, 0, 0);
    }
    __syncthreads();   // protect LDS before next stage
  }
  // epilogue: +bias, relu, bf16 store
#pragma unroll
  for (int n = 0; n < 4; ++n) {
    int col = nt * 128 + wn * 64 + n * 16 + (lane & 15);
    float bias = b1[e * HDIM + col];
#pragma unroll
    for (int m = 0; m < 4; ++m) {
#pragma unroll
      for (int j = 0; j < 4; ++j) {
        int mr = mt * 128 + wm * 64 + m * 16 + ((lane >> 4) << 2) + j;
        if (mr < cnt) {
          float v = fmaxf(acc[m][n][j] + bias, 0.f);
          hbuf[(size_t)(off + mr) * HDIM + col] = (__bf16)v;
        }
      }
    }
  }
}

// ---------------- GEMM2 (K-split): ybuf[slot,:] += hbuf[slot]·W2bf[e]^T ----------------
__global__ __launch_bounds__(256)
void gemm2_kernel(const __bf16* __restrict__ hbuf, const __bf16* __restrict__ w2bf,
                  const int* __restrict__ ecount, const int* __restrict__ offs,
                  float* __restrict__ ybuf)
{
  const int NTILE = DDIM / 128;   // 8
  const int MTILE = NTOK / 128;   // 16
  int bid = blockIdx.x;
  int e = bid / (MTILE * NTILE * KSPLIT);
  int rem = bid % (MTILE * NTILE * KSPLIT);
  int mt = rem / (NTILE * KSPLIT);
  int rem2 = rem % (NTILE * KSPLIT);
  int nt = rem2 / KSPLIT, kc = rem2 % KSPLIT;
  int cnt = ecount[e];
  if (mt * 128 >= cnt) return;
  int off = offs[e];

  __shared__ __bf16 At[128 * 64];
  __shared__ __bf16 Bt[128 * 64];

  int tid = threadIdx.x, lane = tid & 63, wave = tid >> 6;
  int wm = wave >> 1, wn = wave & 1;

  const __bf16* aP[4];
  const __bf16* bP[4];
#pragma unroll
  for (int r = 0; r < 4; ++r) {
    int row = r * 32 + wave * 8 + (lane >> 3);
    aP[r] = hbuf + (size_t)(off + mt * 128 + row) * HDIM + (lane & 7) * 8;
    bP[r] = w2bf + (size_t)e * DDIM * HDIM + (size_t)(nt * 128 + row) * HDIM + (lane & 7) * 8;
  }
  __bf16* lA = At + wave * 512;
  __bf16* lB = Bt + wave * 512;

  f32x4 acc[4][4];
#pragma unroll
  for (int m = 0; m < 4; ++m)
#pragma unroll
    for (int n = 0; n < 4; ++n) acc[m][n] = (f32x4){0.f, 0.f, 0.f, 0.f};

  int kbeg = kc * (HDIM / KSPLIT);
  int kend = kbeg + (HDIM / KSPLIT);
  for (int k0 = kbeg; k0 < kend; k0 += 64) {
#pragma unroll
    for (int r = 0; r < 4; ++r) {
      gld16(aP[r] + k0, lA + r * 2048);
      gld16(bP[r] + k0, lB + r * 2048);
    }
    __syncthreads();
#pragma unroll
    for (int ks = 0; ks < 2; ++ks) {
      int koff = ks * 32 + (lane >> 4) * 8;
      bf16x8 af[4], bfr[4];
#pragma unroll
      for (int m = 0; m < 4; ++m) af[m] = *(const bf16x8*)&At[(wm*64 + m*16 + (lane & 15)) * 64 + koff];
#pragma unroll
      for (int n = 0; n < 4; ++n) bfr[n] = *(const bf16x8*)&Bt[(wn*64 + n*16 + (lane & 15)) * 64 + koff];
#pragma unroll
      for (int m = 0; m < 4; ++m)
#pragma unroll
        for (int n = 0; n < 4; ++n)
          acc[m][n] = __builtin_amdgcn_mfma_f32_16x16x32_bf16(af[m], bfr[n], acc[m][n], 0, 0, 0);
    }
    __syncthreads();
  }
  // epilogue: atomic accumulate raw partials (bias+gate weight in combine)
#pragma unroll
  for (int m = 0; m < 4; ++m) {
#pragma unroll
    for (int j = 0; j < 4; ++j) {
      int mr = mt * 128 + wm * 64 + m * 16 + ((lane >> 4) << 2) + j;
      if (mr >= cnt) continue;
      int slot = off + mr;
#pragma unroll
      for (int n = 0; n < 4; ++n) {
        int col = nt * 128 + wn * 64 + n * 16 + (lane & 15);
        atomicAdd(&ybuf[(size_t)slot * DDIM + col], acc[m][n][j]);
      }
    }
  }
}

// ---------------- combine: out[t] = wA*(y[sA]+b2[eA]) + wB*(y[sB]+b2[eB]) ----------------
__global__ __launch_bounds__(256)
void combine_kernel(const float* __restrict__ ybuf, const int* __restrict__ slot_of,
                    const int* __restrict__ tix, const float* __restrict__ twt,
                    const float* __restrict__ b2, float* __restrict__ out)
{
  int t = blockIdx.x;
  int d4 = threadIdx.x;
  int sA = slot_of[2*t], sB = slot_of[2*t + 1];
  f32x4 r = (f32x4){0.f, 0.f, 0.f, 0.f};
  if (sA >= 0) {
    float wA = twt[2*t];
    f32x4 y = ((const f32x4*)(ybuf + (size_t)sA * DDIM))[d4];
    f32x4 b = ((const f32x4*)(b2 + (size_t)tix[2*t] * DDIM))[d4];
    r += wA * (y + b);
  }
  if (sB >= 0) {
    float wB = twt[2*t + 1];
    f32x4 y = ((const f32x4*)(ybuf + (size_t)sB * DDIM))[d4];
    f32x4 b = ((const f32x4*)(b2 + (size_t)tix[2*t + 1] * DDIM))[d4];
    r += wB * (y + b);
  }
  ((f32x4*)(out + (size_t)t * DDIM))[d4] = r;
}

extern "C" void kernel_launch(void* const* d_in, const int* in_sizes, int n_in,
                              void* d_out, int out_size, void* d_ws, size_t ws_size,
                              hipStream_t stream)
{
  const float* x  = (const float*)d_in[0];
  const unsigned char* pm = (const unsigned char*)d_in[1];
  const float* Wg = (const float*)d_in[2];
  const float* W1 = (const float*)d_in[3];
  const float* b1 = (const float*)d_in[4];
  const float* W2 = (const float*)d_in[5];
  const float* b2 = (const float*)d_in[6];
  float* out = (float*)d_out;
  float* gate_out = out + (size_t)NTOK * DDIM;        // 2097152
  float* lb_out = gate_out + (size_t)NTOK * NEXP;     // 2113536

  char* w = (char*)d_ws;
  int*   ecount   = (int*)(w + 0);
  int*   offs     = (int*)(w + 64);
  int*   fill     = (int*)(w + 128);
  int*   tix      = (int*)(w + 512);                       // 16 KB
  float* twt      = (float*)(w + 512 + 16384);             // 16 KB
  int*   tok_list = (int*)(w + 512 + 32768);               // 16 KB
  int*   slot_of  = (int*)(w + 512 + 49152);               // 16 KB
  uintptr_t p = ((uintptr_t)(w + 512 + 65536) + 255) & ~(uintptr_t)255;
  __bf16* xbf  = (__bf16*)p;                                    // 4 MB
  p += (size_t)NTOK * DDIM * 2;
  __bf16* wbf  = (__bf16*)p;                                    // 67 MB (W1bf, then W2bf)
  p += (size_t)NEXP * HDIM * DDIM * 2;
  __bf16* hbuf = (__bf16*)p;                                    // 33 MB
  p += (size_t)(2 * NTOK + 128) * HDIM * 2;
  float*  ybuf = (float*)p;                                     // 16 MB

  init_kernel<<<1, 64, 0, stream>>>(fill);
  conv_kernel<<<2048, 256, 0, stream>>>(W1, wbf, (long)NEXP * HDIM * DDIM / 8);
  zero_y_kernel<<<(2 * NTOK * DDIM / 4) / 256, 256, 0, stream>>>(ybuf);
  gate_kernel<<<NTOK / 4, 256, 0, stream>>>(x, pm, Wg, gate_out, tix, twt, xbf);
  stats_kernel<<<1, 1024, 0, stream>>>(gate_out, tix, pm, ecount, offs, lb_out);
  compact_kernel<<<NTOK / 256, 256, 0, stream>>>(pm, tix, offs, fill, tok_list, slot_of);
  gemm1_kernel<<<NEXP * (NTOK / 128) * (HDIM / 128), 256, 0, stream>>>(xbf, wbf, b1, ecount, offs, tok_list, hbuf);
  conv_kernel<<<2048, 256, 0, stream>>>(W2, wbf, (long)NEXP * DDIM * HDIM / 8);
  gemm2_kernel<<<NEXP * (NTOK / 128) * (DDIM / 128) * KSPLIT, 256, 0, stream>>>(hbuf, wbf, ecount, offs, ybuf);
  combine_kernel<<<NTOK, 256, 0, stream>>>(ybuf, slot_of, tix, twt, b2, out);
}

// Round 5
// 267.280 us; speedup vs baseline: 2.8094x; 1.1248x over previous
//
#include <hip/hip_runtime.h>
#include <hip/hip_bf16.h>
#include <stdint.h>

// MoE top-2 of 8 experts.  B=2,T=1024 -> nt=2048 tokens, D=1024, H=4096, E=8.
// d_out layout: out[2*1024*1024] f32 | gate_value[2048*8] f32 | lb_loss[1] f32.
//
// R5: GEMMs get (a) double-buffered LDS with prefetch-before-compute
// (T3 minimum recipe: stage(t+1); ds_read+MFMA(t); one vmcnt0+barrier),
// (b) BK=32 keeping LDS at 32KB with dbuf, (c) bank-uniform LDS slot
// swizzle via pre-swizzled GLOBAL source + XOR'd read (rule #21: linear
// gload_lds dest, chunk^((row>>1)&3)), (d) gemm2 KSPLIT 4->2.

#define NTOK 2048
#define DDIM 1024
#define HDIM 4096
#define NEXP 8
#define KSPLIT 2

typedef float  f32x4  __attribute__((ext_vector_type(4)));
typedef __bf16 bf16x8 __attribute__((ext_vector_type(8)));
typedef __bf16 bf16x4 __attribute__((ext_vector_type(4)));

typedef const __attribute__((address_space(1))) void g1_t;
typedef __attribute__((address_space(3))) void l3_t;
__device__ __forceinline__ void gld16(const void* g, void* l) {
  // async global->LDS, 16B/lane; LDS dest = wave-uniform base + lane*16
  __builtin_amdgcn_global_load_lds((g1_t*)g, (l3_t*)l, 16, 0, 0);
}

// ---------------- init: zero the fill counters ----------------
__global__ void init_kernel(int* fill) {
  int t = threadIdx.x;
  if (t < NEXP) fill[t] = 0;
}

// ---------------- f32 -> bf16 bulk convert (grid-stride, 8 elems/thread) ----------------
__global__ __launch_bounds__(256)
void conv_kernel(const float* __restrict__ src, __bf16* __restrict__ dst, long n8) {
  long i = (long)blockIdx.x * 256 + threadIdx.x;
  long stride = (long)gridDim.x * 256;
  for (; i < n8; i += stride) {
    f32x4 a = ((const f32x4*)src)[2 * i];
    f32x4 b = ((const f32x4*)src)[2 * i + 1];
    bf16x8 o;
#pragma unroll
    for (int q = 0; q < 4; ++q) { o[q] = (__bf16)a[q]; o[q + 4] = (__bf16)b[q]; }
    ((bf16x8*)dst)[i] = o;
  }
}

// ---------------- zero ybuf (gemm2 accumulates with atomics) ----------------
__global__ __launch_bounds__(256)
void zero_y_kernel(float* __restrict__ y) {
  size_t i = (size_t)blockIdx.x * 256 + threadIdx.x;
  ((f32x4*)y)[i] = (f32x4){0.f, 0.f, 0.f, 0.f};
}

// ---------------- gate: logits, softmax, top2; emits xbf.  NO atomics. ----------------
__global__ __launch_bounds__(256)
void gate_kernel(const float* __restrict__ x, const unsigned char* __restrict__ pmask,
                 const float* __restrict__ Wg, float* __restrict__ gate_out,
                 int* __restrict__ tix, float* __restrict__ twt,
                 __bf16* __restrict__ xbf)
{
  int wave = threadIdx.x >> 6, lane = threadIdx.x & 63;
  int t = blockIdx.x * 4 + wave;   // one wave per token
  const f32x4* x4 = (const f32x4*)(x + (size_t)t * DDIM);
  const f32x4* w4 = (const f32x4*)Wg;
  bf16x4* xb4 = (bf16x4*)(xbf + (size_t)t * DDIM);
  float acc[NEXP];
#pragma unroll
  for (int e = 0; e < NEXP; ++e) acc[e] = 0.f;
#pragma unroll
  for (int i = 0; i < 4; ++i) {
    f32x4 xv = x4[i * 64 + lane];
    bf16x4 xo;
#pragma unroll
    for (int q = 0; q < 4; ++q) xo[q] = (__bf16)xv[q];
    xb4[i * 64 + lane] = xo;
#pragma unroll
    for (int e = 0; e < NEXP; ++e) {
      f32x4 wv = w4[e * 256 + i * 64 + lane];
      acc[e] += xv[0]*wv[0] + xv[1]*wv[1] + xv[2]*wv[2] + xv[3]*wv[3];
    }
  }
#pragma unroll
  for (int e = 0; e < NEXP; ++e) {
    float v = acc[e];
#pragma unroll
    for (int off = 32; off > 0; off >>= 1) v += __shfl_xor(v, off, 64);
    acc[e] = v;
  }
  if (lane == 0) {
    bool pm = pmask[t] != 0;
    float m = acc[0];
#pragma unroll
    for (int e = 1; e < NEXP; ++e) m = fmaxf(m, acc[e]);
    float g[NEXP]; float s = 0.f;
#pragma unroll
    for (int e = 0; e < NEXP; ++e) { g[e] = expf(acc[e] - m); s += g[e]; }
    float inv = 1.f / s;
#pragma unroll
    for (int e = 0; e < NEXP; ++e) g[e] *= inv;
    if (pm) {
#pragma unroll
      for (int e = 0; e < NEXP; ++e) g[e] = 0.f;
    }
    int i1 = 0;
#pragma unroll
    for (int e = 1; e < NEXP; ++e) if (g[e] > g[i1]) i1 = e;
    int i2 = -1;
#pragma unroll
    for (int e = 0; e < NEXP; ++e) if (e != i1 && (i2 < 0 || g[e] > g[i2])) i2 = e;
    float w1 = g[i1], w2 = g[i2], ss = w1 + w2;
    if (ss == 0.f) ss = 1.f;
    w1 /= ss; w2 /= ss;
#pragma unroll
    for (int e = 0; e < NEXP; ++e) gate_out[(size_t)t * NEXP + e] = g[e];
    tix[2*t] = i1; tix[2*t+1] = i2;
    twt[2*t] = w1; twt[2*t+1] = w2;
  }
}

// ---------------- stats: single-block tree reduce -> ecount/offs/lb ----------------
__global__ __launch_bounds__(1024)
void stats_kernel(const float* __restrict__ gate_out, const int* __restrict__ tix,
                  const unsigned char* __restrict__ pmask,
                  int* __restrict__ ecount, int* __restrict__ offs,
                  float* __restrict__ lb_out)
{
  int tid = threadIdx.x, lane = tid & 63, wv = tid >> 6;   // 16 waves
  float lg[NEXP]; float lt1[NEXP]; int lec[NEXP]; float ln = 0.f;
#pragma unroll
  for (int e = 0; e < NEXP; ++e) { lg[e] = 0.f; lt1[e] = 0.f; lec[e] = 0; }
#pragma unroll
  for (int it = 0; it < NTOK / 1024; ++it) {
    int t = tid + it * 1024;
    f32x4 g0 = ((const f32x4*)(gate_out + (size_t)t * NEXP))[0];
    f32x4 g1 = ((const f32x4*)(gate_out + (size_t)t * NEXP))[1];
    lg[0] += g0[0]; lg[1] += g0[1]; lg[2] += g0[2]; lg[3] += g0[3];
    lg[4] += g1[0]; lg[5] += g1[1]; lg[6] += g1[2]; lg[7] += g1[3];
    if (!pmask[t]) {
      int i1 = tix[2*t], i2 = tix[2*t+1];
      lt1[i1] += 1.f; lec[i1] += 1; lec[i2] += 1; ln += 1.f;
    }
  }
#pragma unroll
  for (int e = 0; e < NEXP; ++e) {
#pragma unroll
    for (int off = 32; off > 0; off >>= 1) {
      lg[e]  += __shfl_xor(lg[e],  off, 64);
      lt1[e] += __shfl_xor(lt1[e], off, 64);
      lec[e] += __shfl_xor(lec[e], off, 64);
    }
  }
#pragma unroll
  for (int off = 32; off > 0; off >>= 1) ln += __shfl_xor(ln, off, 64);
  __shared__ float sg[16][NEXP], st[16][NEXP], sn[16];
  __shared__ int   se[16][NEXP];
  if (lane == 0) {
#pragma unroll
    for (int e = 0; e < NEXP; ++e) { sg[wv][e] = lg[e]; st[wv][e] = lt1[e]; se[wv][e] = lec[e]; }
    sn[wv] = ln;
  }
  __syncthreads();
  if (tid == 0) {
    float G[NEXP] = {0}, T1[NEXP] = {0}; int EC[NEXP] = {0}; float N = 0.f;
    for (int w = 0; w < 16; ++w) {
      N += sn[w];
#pragma unroll
      for (int e = 0; e < NEXP; ++e) { G[e] += sg[w][e]; T1[e] += st[w][e]; EC[e] += se[w][e]; }
    }
    int o = 0;
    for (int e = 0; e < NEXP; ++e) { ecount[e] = EC[e]; offs[e] = o; o += EC[e]; }
    if (N <= 0.f) N = 1.f;
    float lb = 0.f;
    for (int e = 0; e < NEXP; ++e) lb += (T1[e] / N) * (G[e] / N);
    lb_out[0] = (float)NEXP * lb;
  }
}

// ---------------- compaction: ballot-aggregated (1 atomic/wave/expert) ----------------
__global__ __launch_bounds__(256)
void compact_kernel(const unsigned char* __restrict__ pmask, const int* __restrict__ tix,
                    const int* __restrict__ offs, int* __restrict__ fill,
                    int* __restrict__ tok_list, int* __restrict__ slot_of)
{
  int t = blockIdx.x * 256 + threadIdx.x;
  int lane = threadIdx.x & 63;
  bool pm = pmask[t] != 0;
#pragma unroll
  for (int j = 0; j < 2; ++j) {
    int e = pm ? -1 : tix[2*t + j];
    int pos = -1;
#pragma unroll
    for (int ex = 0; ex < NEXP; ++ex) {
      unsigned long long mask = __ballot(e == ex);
      if (mask) {
        int leader = (int)(__ffsll((long long)mask) - 1);
        int base = 0;
        if (lane == leader) base = atomicAdd(&fill[ex], (int)__popcll(mask));
        base = __shfl(base, leader, 64);
        if (e == ex)
          pos = offs[ex] + base + (int)__popcll(mask & ((1ull << lane) - 1ull));
      }
    }
    if (e >= 0) { tok_list[pos] = t; slot_of[2*t + j] = pos; }
    else slot_of[2*t + j] = -1;
  }
}

// ======================= GEMM cores (R5) =======================
// 128x128 tile, BK=32, dbuf LDS A[2]/B[2] (32KB total), 4 waves (2x2),
// mfma 16x16x32 bf16, 4x4 frags.  Swizzle: LDS slot (row, cs) holds data
// chunk cd = cs ^ ((row>>1)&3)  (chunk = 16B = 8 bf16).  gload_lds dest is
// linear; the swizzle is applied on the per-lane GLOBAL source address and
// undone on the fragment ds_read address.

// ---------------- GEMM1: h[slot,:] = relu(xbf[tok]·W1bf[e]^T + b1[e]) ----------------
__global__ __launch_bounds__(256)
void gemm1_kernel(const __bf16* __restrict__ xbf, const __bf16* __restrict__ w1bf,
                  const float* __restrict__ b1, const int* __restrict__ ecount,
                  const int* __restrict__ offs, const int* __restrict__ tok_list,
                  __bf16* __restrict__ hbuf)
{
  const int NTILE = HDIM / 128;   // 32
  const int MTILE = NTOK / 128;   // 16
  int bid = blockIdx.x;
  int e = bid / (MTILE * NTILE);
  int rem = bid % (MTILE * NTILE);
  int mt = rem / NTILE, nt = rem % NTILE;
  int cnt = ecount[e];
  if (mt * 128 >= cnt) return;
  int off = offs[e];

  __shared__ __bf16 As[2][128 * 32];
  __shared__ __bf16 Bs[2][128 * 32];

  int tid = threadIdx.x, lane = tid & 63, wave = tid >> 6;
  int wm = wave >> 1, wn = wave & 1;

  // staging pointers: call c stages rows c*64 + (tid>>2), 16B chunk cs=tid&3,
  // fetching data chunk cd = cs ^ ((row>>1)&3)
  const __bf16* aP[2];
  const __bf16* bP[2];
#pragma unroll
  for (int c = 0; c < 2; ++c) {
    int row = c * 64 + (tid >> 2);
    int cd = (tid & 3) ^ ((row >> 1) & 3);
    int mrow = mt * 128 + row;
    int tok = tok_list[off + ((mrow < cnt) ? mrow : 0)];
    aP[c] = xbf + (size_t)tok * DDIM + cd * 8;
    bP[c] = w1bf + (size_t)e * HDIM * DDIM + (size_t)(nt * 128 + row) * DDIM + cd * 8;
  }
  // fragment-read chunk offset (elements), undoing the swizzle: per-lane const
  int cg = ((lane >> 4) ^ ((lane >> 1) & 3)) << 3;

  f32x4 acc[4][4];
#pragma unroll
  for (int m = 0; m < 4; ++m)
#pragma unroll
    for (int n = 0; n < 4; ++n) acc[m][n] = (f32x4){0.f, 0.f, 0.f, 0.f};

  const int NIT = DDIM / 32;   // 32
  // prologue: stage tile 0
#pragma unroll
  for (int c = 0; c < 2; ++c) {
    gld16(aP[c], &As[0][(c * 64 + wave * 16) * 32]);
    gld16(bP[c], &Bs[0][(c * 64 + wave * 16) * 32]);
  }
  __syncthreads();

  for (int it = 0; it < NIT; ++it) {
    int cur = it & 1;
    if (it + 1 < NIT) {          // prefetch next tile into the other buffer
      int k0 = (it + 1) * 32;
#pragma unroll
      for (int c = 0; c < 2; ++c) {
        gld16(aP[c] + k0, &As[cur ^ 1][(c * 64 + wave * 16) * 32]);
        gld16(bP[c] + k0, &Bs[cur ^ 1][(c * 64 + wave * 16) * 32]);
      }
    }
    bf16x8 af[4], bfr[4];
#pragma unroll
    for (int m = 0; m < 4; ++m) af[m]  = *(const bf16x8*)&As[cur][(wm*64 + m*16 + (lane & 15)) * 32 + cg];
#pragma unroll
    for (int n = 0; n < 4; ++n) bfr[n] = *(const bf16x8*)&Bs[cur][(wn*64 + n*16 + (lane & 15)) * 32 + cg];
#pragma unroll
    for (int m = 0; m < 4; ++m)
#pragma unroll
      for (int n = 0; n < 4; ++n)
        acc[m][n] = __builtin_amdgcn_mfma_f32_16x16x32_bf16(af[m], bfr[n], acc[m][n], 0, 0, 0);
    __syncthreads();   // drains vmcnt(0): next buffer ready; protects cur for overwrite
  }

  // epilogue: +bias, relu, bf16 store
#pragma unroll
  for (int n = 0; n < 4; ++n) {
    int col = nt * 128 + wn * 64 + n * 16 + (lane & 15);
    float bias = b1[e * HDIM + col];
#pragma unroll
    for (int m = 0; m < 4; ++m) {
#pragma unroll
      for (int j = 0; j < 4; ++j) {
        int mr = mt * 128 + wm * 64 + m * 16 + ((lane >> 4) << 2) + j;
        if (mr < cnt) {
          float v = fmaxf(acc[m][n][j] + bias, 0.f);
          hbuf[(size_t)(off + mr) * HDIM + col] = (__bf16)v;
        }
      }
    }
  }
}

// ---------------- GEMM2 (K-split): ybuf[slot,:] += hbuf[slot]·W2bf[e]^T ----------------
__global__ __launch_bounds__(256)
void gemm2_kernel(const __bf16* __restrict__ hbuf, const __bf16* __restrict__ w2bf,
                  const int* __restrict__ ecount, const int* __restrict__ offs,
                  float* __restrict__ ybuf)
{
  const int NTILE = DDIM / 128;   // 8
  const int MTILE = NTOK / 128;   // 16
  int bid = blockIdx.x;
  int e = bid / (MTILE * NTILE * KSPLIT);
  int rem = bid % (MTILE * NTILE * KSPLIT);
  int mt = rem / (NTILE * KSPLIT);
  int rem2 = rem % (NTILE * KSPLIT);
  int nt = rem2 / KSPLIT, kc = rem2 % KSPLIT;
  int cnt = ecount[e];
  if (mt * 128 >= cnt) return;
  int off = offs[e];

  __shared__ __bf16 As[2][128 * 32];
  __shared__ __bf16 Bs[2][128 * 32];

  int tid = threadIdx.x, lane = tid & 63, wave = tid >> 6;
  int wm = wave >> 1, wn = wave & 1;

  const __bf16* aP[2];
  const __bf16* bP[2];
#pragma unroll
  for (int c = 0; c < 2; ++c) {
    int row = c * 64 + (tid >> 2);
    int cd = (tid & 3) ^ ((row >> 1) & 3);
    aP[c] = hbuf + (size_t)(off + mt * 128 + row) * HDIM + cd * 8;
    bP[c] = w2bf + (size_t)e * DDIM * HDIM + (size_t)(nt * 128 + row) * HDIM + cd * 8;
  }
  int cg = ((lane >> 4) ^ ((lane >> 1) & 3)) << 3;

  f32x4 acc[4][4];
#pragma unroll
  for (int m = 0; m < 4; ++m)
#pragma unroll
    for (int n = 0; n < 4; ++n) acc[m][n] = (f32x4){0.f, 0.f, 0.f, 0.f};

  const int KCH = HDIM / KSPLIT;      // 2048
  const int NIT = KCH / 32;           // 64
  int kbeg = kc * KCH;
#pragma unroll
  for (int c = 0; c < 2; ++c) {
    gld16(aP[c] + kbeg, &As[0][(c * 64 + wave * 16) * 32]);
    gld16(bP[c] + kbeg, &Bs[0][(c * 64 + wave * 16) * 32]);
  }
  __syncthreads();

  for (int it = 0; it < NIT; ++it) {
    int cur = it & 1;
    if (it + 1 < NIT) {
      int k0 = kbeg + (it + 1) * 32;
#pragma unroll
      for (int c = 0; c < 2; ++c) {
        gld16(aP[c] + k0, &As[cur ^ 1][(c * 64 + wave * 16) * 32]);
        gld16(bP[c] + k0, &Bs[cur ^ 1][(c * 64 + wave * 16) * 32]);
      }
    }
    bf16x8 af[4], bfr[4];
#pragma unroll
    for (int m = 0; m < 4; ++m) af[m]  = *(const bf16x8*)&As[cur][(wm*64 + m*16 + (lane & 15)) * 32 + cg];
#pragma unroll
    for (int n = 0; n < 4; ++n) bfr[n] = *(const bf16x8*)&Bs[cur][(wn*64 + n*16 + (lane & 15)) * 32 + cg];
#pragma unroll
    for (int m = 0; m < 4; ++m)
#pragma unroll
      for (int n = 0; n < 4; ++n)
        acc[m][n] = __builtin_amdgcn_mfma_f32_16x16x32_bf16(af[m], bfr[n], acc[m][n], 0, 0, 0);
    __syncthreads();
  }

  // epilogue: atomic accumulate raw partials (bias+gate weight in combine)
#pragma unroll
  for (int m = 0; m < 4; ++m) {
#pragma unroll
    for (int j = 0; j < 4; ++j) {
      int mr = mt * 128 + wm * 64 + m * 16 + ((lane >> 4) << 2) + j;
      if (mr >= cnt) continue;
      int slot = off + mr;
#pragma unroll
      for (int n = 0; n < 4; ++n) {
        int col = nt * 128 + wn * 64 + n * 16 + (lane & 15);
        atomicAdd(&ybuf[(size_t)slot * DDIM + col], acc[m][n][j]);
      }
    }
  }
}

// ---------------- combine: out[t] = wA*(y[sA]+b2[eA]) + wB*(y[sB]+b2[eB]) ----------------
__global__ __launch_bounds__(256)
void combine_kernel(const float* __restrict__ ybuf, const int* __restrict__ slot_of,
                    const int* __restrict__ tix, const float* __restrict__ twt,
                    const float* __restrict__ b2, float* __restrict__ out)
{
  int t = blockIdx.x;
  int d4 = threadIdx.x;
  int sA = slot_of[2*t], sB = slot_of[2*t + 1];
  f32x4 r = (f32x4){0.f, 0.f, 0.f, 0.f};
  if (sA >= 0) {
    float wA = twt[2*t];
    f32x4 y = ((const f32x4*)(ybuf + (size_t)sA * DDIM))[d4];
    f32x4 b = ((const f32x4*)(b2 + (size_t)tix[2*t] * DDIM))[d4];
    r += wA * (y + b);
  }
  if (sB >= 0) {
    float wB = twt[2*t + 1];
    f32x4 y = ((const f32x4*)(ybuf + (size_t)sB * DDIM))[d4];
    f32x4 b = ((const f32x4*)(b2 + (size_t)tix[2*t + 1] * DDIM))[d4];
    r += wB * (y + b);
  }
  ((f32x4*)(out + (size_t)t * DDIM))[d4] = r;
}

extern "C" void kernel_launch(void* const* d_in, const int* in_sizes, int n_in,
                              void* d_out, int out_size, void* d_ws, size_t ws_size,
                              hipStream_t stream)
{
  const float* x  = (const float*)d_in[0];
  const unsigned char* pm = (const unsigned char*)d_in[1];
  const float* Wg = (const float*)d_in[2];
  const float* W1 = (const float*)d_in[3];
  const float* b1 = (const float*)d_in[4];
  const float* W2 = (const float*)d_in[5];
  const float* b2 = (const float*)d_in[6];
  float* out = (float*)d_out;
  float* gate_out = out + (size_t)NTOK * DDIM;        // 2097152
  float* lb_out = gate_out + (size_t)NTOK * NEXP;     // 2113536

  char* w = (char*)d_ws;
  int*   ecount   = (int*)(w + 0);
  int*   offs     = (int*)(w + 64);
  int*   fill     = (int*)(w + 128);
  int*   tix      = (int*)(w + 512);                       // 16 KB
  float* twt      = (float*)(w + 512 + 16384);             // 16 KB
  int*   tok_list = (int*)(w + 512 + 32768);               // 16 KB
  int*   slot_of  = (int*)(w + 512 + 49152);               // 16 KB
  uintptr_t p = ((uintptr_t)(w + 512 + 65536) + 255) & ~(uintptr_t)255;
  __bf16* xbf  = (__bf16*)p;                                    // 4 MB
  p += (size_t)NTOK * DDIM * 2;
  __bf16* wbf  = (__bf16*)p;                                    // 67 MB (W1bf, then W2bf)
  p += (size_t)NEXP * HDIM * DDIM * 2;
  __bf16* hbuf = (__bf16*)p;                                    // 33 MB
  p += (size_t)(2 * NTOK + 128) * HDIM * 2;
  float*  ybuf = (float*)p;                                     // 16 MB

  init_kernel<<<1, 64, 0, stream>>>(fill);
  conv_kernel<<<2048, 256, 0, stream>>>(W1, wbf, (long)NEXP * HDIM * DDIM / 8);
  zero_y_kernel<<<(2 * NTOK * DDIM / 4) / 256, 256, 0, stream>>>(ybuf);
  gate_kernel<<<NTOK / 4, 256, 0, stream>>>(x, pm, Wg, gate_out, tix, twt, xbf);
  stats_kernel<<<1, 1024, 0, stream>>>(gate_out, tix, pm, ecount, offs, lb_out);
  compact_kernel<<<NTOK / 256, 256, 0, stream>>>(pm, tix, offs, fill, tok_list, slot_of);
  gemm1_kernel<<<NEXP * (NTOK / 128) * (HDIM / 128), 256, 0, stream>>>(xbf, wbf, b1, ecount, offs, tok_list, hbuf);
  conv_kernel<<<2048, 256, 0, stream>>>(W2, wbf, (long)NEXP * DDIM * HDIM / 8);
  gemm2_kernel<<<NEXP * (NTOK / 128) * (DDIM / 128) * KSPLIT, 256, 0, stream>>>(hbuf, wbf, ecount, offs, ybuf);
  combine_kernel<<<NTOK, 256, 0, stream>>>(ybuf, slot_of, tix, twt, b2, out);
}

// Round 6
// 258.821 us; speedup vs baseline: 2.9012x; 1.0327x over previous
//
#include <hip/hip_runtime.h>
#include <hip/hip_bf16.h>
#include <stdint.h>

// MoE top-2 of 8 experts.  B=2,T=1024 -> nt=2048 tokens, D=1024, H=4096, E=8.
// d_out layout: out[2*1024*1024] f32 | gate_value[2048*8] f32 | lb_loss[1] f32.
//
// R6: GEMM K-loop -> 3-buffer ring, 2-deep prefetch, counted vmcnt(4)
// (T4: never drain vmcnt to 0 in the main loop), raw s_barrier (one per
// K-step), sched_barrier(0) pin after barrier (rule #18).  Swizzle from R5
// kept (bank conflicts measured 0).

#define NTOK 2048
#define DDIM 1024
#define HDIM 4096
#define NEXP 8
#define KSPLIT 2

typedef float  f32x4  __attribute__((ext_vector_type(4)));
typedef __bf16 bf16x8 __attribute__((ext_vector_type(8)));
typedef __bf16 bf16x4 __attribute__((ext_vector_type(4)));

typedef const __attribute__((address_space(1))) void g1_t;
typedef __attribute__((address_space(3))) void l3_t;
__device__ __forceinline__ void gld16(const void* g, void* l) {
  // async global->LDS, 16B/lane; LDS dest = wave-uniform base + lane*16
  __builtin_amdgcn_global_load_lds((g1_t*)g, (l3_t*)l, 16, 0, 0);
}

// ---------------- init: zero the fill counters ----------------
__global__ void init_kernel(int* fill) {
  int t = threadIdx.x;
  if (t < NEXP) fill[t] = 0;
}

// ---------------- f32 -> bf16 bulk convert (grid-stride, 8 elems/thread) ----------------
__global__ __launch_bounds__(256)
void conv_kernel(const float* __restrict__ src, __bf16* __restrict__ dst, long n8) {
  long i = (long)blockIdx.x * 256 + threadIdx.x;
  long stride = (long)gridDim.x * 256;
  for (; i < n8; i += stride) {
    f32x4 a = ((const f32x4*)src)[2 * i];
    f32x4 b = ((const f32x4*)src)[2 * i + 1];
    bf16x8 o;
#pragma unroll
    for (int q = 0; q < 4; ++q) { o[q] = (__bf16)a[q]; o[q + 4] = (__bf16)b[q]; }
    ((bf16x8*)dst)[i] = o;
  }
}

// ---------------- zero ybuf (gemm2 accumulates with atomics) ----------------
__global__ __launch_bounds__(256)
void zero_y_kernel(float* __restrict__ y) {
  size_t i = (size_t)blockIdx.x * 256 + threadIdx.x;
  ((f32x4*)y)[i] = (f32x4){0.f, 0.f, 0.f, 0.f};
}

// ---------------- gate: logits, softmax, top2; emits xbf.  NO atomics. ----------------
__global__ __launch_bounds__(256)
void gate_kernel(const float* __restrict__ x, const unsigned char* __restrict__ pmask,
                 const float* __restrict__ Wg, float* __restrict__ gate_out,
                 int* __restrict__ tix, float* __restrict__ twt,
                 __bf16* __restrict__ xbf)
{
  int wave = threadIdx.x >> 6, lane = threadIdx.x & 63;
  int t = blockIdx.x * 4 + wave;   // one wave per token
  const f32x4* x4 = (const f32x4*)(x + (size_t)t * DDIM);
  const f32x4* w4 = (const f32x4*)Wg;
  bf16x4* xb4 = (bf16x4*)(xbf + (size_t)t * DDIM);
  float acc[NEXP];
#pragma unroll
  for (int e = 0; e < NEXP; ++e) acc[e] = 0.f;
#pragma unroll
  for (int i = 0; i < 4; ++i) {
    f32x4 xv = x4[i * 64 + lane];
    bf16x4 xo;
#pragma unroll
    for (int q = 0; q < 4; ++q) xo[q] = (__bf16)xv[q];
    xb4[i * 64 + lane] = xo;
#pragma unroll
    for (int e = 0; e < NEXP; ++e) {
      f32x4 wv = w4[e * 256 + i * 64 + lane];
      acc[e] += xv[0]*wv[0] + xv[1]*wv[1] + xv[2]*wv[2] + xv[3]*wv[3];
    }
  }
#pragma unroll
  for (int e = 0; e < NEXP; ++e) {
    float v = acc[e];
#pragma unroll
    for (int off = 32; off > 0; off >>= 1) v += __shfl_xor(v, off, 64);
    acc[e] = v;
  }
  if (lane == 0) {
    bool pm = pmask[t] != 0;
    float m = acc[0];
#pragma unroll
    for (int e = 1; e < NEXP; ++e) m = fmaxf(m, acc[e]);
    float g[NEXP]; float s = 0.f;
#pragma unroll
    for (int e = 0; e < NEXP; ++e) { g[e] = expf(acc[e] - m); s += g[e]; }
    float inv = 1.f / s;
#pragma unroll
    for (int e = 0; e < NEXP; ++e) g[e] *= inv;
    if (pm) {
#pragma unroll
      for (int e = 0; e < NEXP; ++e) g[e] = 0.f;
    }
    int i1 = 0;
#pragma unroll
    for (int e = 1; e < NEXP; ++e) if (g[e] > g[i1]) i1 = e;
    int i2 = -1;
#pragma unroll
    for (int e = 0; e < NEXP; ++e) if (e != i1 && (i2 < 0 || g[e] > g[i2])) i2 = e;
    float w1 = g[i1], w2 = g[i2], ss = w1 + w2;
    if (ss == 0.f) ss = 1.f;
    w1 /= ss; w2 /= ss;
#pragma unroll
    for (int e = 0; e < NEXP; ++e) gate_out[(size_t)t * NEXP + e] = g[e];
    tix[2*t] = i1; tix[2*t+1] = i2;
    twt[2*t] = w1; twt[2*t+1] = w2;
  }
}

// ---------------- stats: single-block tree reduce -> ecount/offs/lb ----------------
__global__ __launch_bounds__(1024)
void stats_kernel(const float* __restrict__ gate_out, const int* __restrict__ tix,
                  const unsigned char* __restrict__ pmask,
                  int* __restrict__ ecount, int* __restrict__ offs,
                  float* __restrict__ lb_out)
{
  int tid = threadIdx.x, lane = tid & 63, wv = tid >> 6;   // 16 waves
  float lg[NEXP]; float lt1[NEXP]; int lec[NEXP]; float ln = 0.f;
#pragma unroll
  for (int e = 0; e < NEXP; ++e) { lg[e] = 0.f; lt1[e] = 0.f; lec[e] = 0; }
#pragma unroll
  for (int it = 0; it < NTOK / 1024; ++it) {
    int t = tid + it * 1024;
    f32x4 g0 = ((const f32x4*)(gate_out + (size_t)t * NEXP))[0];
    f32x4 g1 = ((const f32x4*)(gate_out + (size_t)t * NEXP))[1];
    lg[0] += g0[0]; lg[1] += g0[1]; lg[2] += g0[2]; lg[3] += g0[3];
    lg[4] += g1[0]; lg[5] += g1[1]; lg[6] += g1[2]; lg[7] += g1[3];
    if (!pmask[t]) {
      int i1 = tix[2*t], i2 = tix[2*t+1];
      lt1[i1] += 1.f; lec[i1] += 1; lec[i2] += 1; ln += 1.f;
    }
  }
#pragma unroll
  for (int e = 0; e < NEXP; ++e) {
#pragma unroll
    for (int off = 32; off > 0; off >>= 1) {
      lg[e]  += __shfl_xor(lg[e],  off, 64);
      lt1[e] += __shfl_xor(lt1[e], off, 64);
      lec[e] += __shfl_xor(lec[e], off, 64);
    }
  }
#pragma unroll
  for (int off = 32; off > 0; off >>= 1) ln += __shfl_xor(ln, off, 64);
  __shared__ float sg[16][NEXP], st[16][NEXP], sn[16];
  __shared__ int   se[16][NEXP];
  if (lane == 0) {
#pragma unroll
    for (int e = 0; e < NEXP; ++e) { sg[wv][e] = lg[e]; st[wv][e] = lt1[e]; se[wv][e] = lec[e]; }
    sn[wv] = ln;
  }
  __syncthreads();
  if (tid == 0) {
    float G[NEXP] = {0}, T1[NEXP] = {0}; int EC[NEXP] = {0}; float N = 0.f;
    for (int w = 0; w < 16; ++w) {
      N += sn[w];
#pragma unroll
      for (int e = 0; e < NEXP; ++e) { G[e] += sg[w][e]; T1[e] += st[w][e]; EC[e] += se[w][e]; }
    }
    int o = 0;
    for (int e = 0; e < NEXP; ++e) { ecount[e] = EC[e]; offs[e] = o; o += EC[e]; }
    if (N <= 0.f) N = 1.f;
    float lb = 0.f;
    for (int e = 0; e < NEXP; ++e) lb += (T1[e] / N) * (G[e] / N);
    lb_out[0] = (float)NEXP * lb;
  }
}

// ---------------- compaction: ballot-aggregated (1 atomic/wave/expert) ----------------
__global__ __launch_bounds__(256)
void compact_kernel(const unsigned char* __restrict__ pmask, const int* __restrict__ tix,
                    const int* __restrict__ offs, int* __restrict__ fill,
                    int* __restrict__ tok_list, int* __restrict__ slot_of)
{
  int t = blockIdx.x * 256 + threadIdx.x;
  int lane = threadIdx.x & 63;
  bool pm = pmask[t] != 0;
#pragma unroll
  for (int j = 0; j < 2; ++j) {
    int e = pm ? -1 : tix[2*t + j];
    int pos = -1;
#pragma unroll
    for (int ex = 0; ex < NEXP; ++ex) {
      unsigned long long mask = __ballot(e == ex);
      if (mask) {
        int leader = (int)(__ffsll((long long)mask) - 1);
        int base = 0;
        if (lane == leader) base = atomicAdd(&fill[ex], (int)__popcll(mask));
        base = __shfl(base, leader, 64);
        if (e == ex)
          pos = offs[ex] + base + (int)__popcll(mask & ((1ull << lane) - 1ull));
      }
    }
    if (e >= 0) { tok_list[pos] = t; slot_of[2*t + j] = pos; }
    else slot_of[2*t + j] = -1;
  }
}

// ======================= GEMM cores (R6) =======================
// 128x128 tile, BK=32, 3-buffer LDS ring (48KB), 2-deep prefetch,
// counted s_waitcnt vmcnt(4) + raw s_barrier (ONE per K-step, never
// vmcnt(0) except final iter).  Swizzle (R5): LDS slot (row, cs) holds
// data chunk cd = cs ^ ((row>>1)&3); linear gload_lds dest, swizzle on
// global src + undone on fragment read.
//
// Ring safety: at iter it we compute buf[it%3] and stage tile it+2 into
// buf[(it+2)%3] == buf[(it-1)%3].  All waves' ds_reads of tile it-1
// completed (lgkmcnt(0) precedes their MFMAs) before they reached this
// iter's s_barrier, so the overwrite is ordered.  vmcnt(4) leaves tile
// it+1's 4 loads in flight across the barrier.

// ---------------- GEMM1: h[slot,:] = relu(xbf[tok]·W1bf[e]^T + b1[e]) ----------------
__global__ __launch_bounds__(256)
void gemm1_kernel(const __bf16* __restrict__ xbf, const __bf16* __restrict__ w1bf,
                  const float* __restrict__ b1, const int* __restrict__ ecount,
                  const int* __restrict__ offs, const int* __restrict__ tok_list,
                  __bf16* __restrict__ hbuf)
{
  const int NTILE = HDIM / 128;   // 32
  const int MTILE = NTOK / 128;   // 16
  int bid = blockIdx.x;
  int e = bid / (MTILE * NTILE);
  int rem = bid % (MTILE * NTILE);
  int mt = rem / NTILE, nt = rem % NTILE;
  int cnt = ecount[e];
  if (mt * 128 >= cnt) return;
  int off = offs[e];

  __shared__ __bf16 As[3][128 * 32];
  __shared__ __bf16 Bs[3][128 * 32];

  int tid = threadIdx.x, lane = tid & 63, wave = tid >> 6;
  int wm = wave >> 1, wn = wave & 1;

  const __bf16* aP[2];
  const __bf16* bP[2];
#pragma unroll
  for (int c = 0; c < 2; ++c) {
    int row = c * 64 + (tid >> 2);
    int cd = (tid & 3) ^ ((row >> 1) & 3);
    int mrow = mt * 128 + row;
    int tok = tok_list[off + ((mrow < cnt) ? mrow : 0)];
    aP[c] = xbf + (size_t)tok * DDIM + cd * 8;
    bP[c] = w1bf + (size_t)e * HDIM * DDIM + (size_t)(nt * 128 + row) * DDIM + cd * 8;
  }
  int cg = ((lane >> 4) ^ ((lane >> 1) & 3)) << 3;

  f32x4 acc[4][4];
#pragma unroll
  for (int m = 0; m < 4; ++m)
#pragma unroll
    for (int n = 0; n < 4; ++n) acc[m][n] = (f32x4){0.f, 0.f, 0.f, 0.f};

  const int NIT = DDIM / 32;   // 32
  // prologue: stage tiles 0,1 (8 loads/thread in flight)
#pragma unroll
  for (int pt = 0; pt < 2; ++pt)
#pragma unroll
    for (int c = 0; c < 2; ++c) {
      gld16(aP[c] + pt * 32, &As[pt][(c * 64 + wave * 16) * 32]);
      gld16(bP[c] + pt * 32, &Bs[pt][(c * 64 + wave * 16) * 32]);
    }

  for (int it = 0; it < NIT; ++it) {
    int cur = it % 3;
    if (it + 1 < NIT) asm volatile("s_waitcnt vmcnt(4)" ::: "memory");
    else              asm volatile("s_waitcnt vmcnt(0)" ::: "memory");
    __builtin_amdgcn_s_barrier();
    __builtin_amdgcn_sched_barrier(0);
    if (it + 2 < NIT) {
      int nb = (it + 2) % 3;
      int k0 = (it + 2) * 32;
#pragma unroll
      for (int c = 0; c < 2; ++c) {
        gld16(aP[c] + k0, &As[nb][(c * 64 + wave * 16) * 32]);
        gld16(bP[c] + k0, &Bs[nb][(c * 64 + wave * 16) * 32]);
      }
    }
    bf16x8 af[4], bfr[4];
#pragma unroll
    for (int m = 0; m < 4; ++m) af[m]  = *(const bf16x8*)&As[cur][(wm*64 + m*16 + (lane & 15)) * 32 + cg];
#pragma unroll
    for (int n = 0; n < 4; ++n) bfr[n] = *(const bf16x8*)&Bs[cur][(wn*64 + n*16 + (lane & 15)) * 32 + cg];
#pragma unroll
    for (int m = 0; m < 4; ++m)
#pragma unroll
      for (int n = 0; n < 4; ++n)
        acc[m][n] = __builtin_amdgcn_mfma_f32_16x16x32_bf16(af[m], bfr[n], acc[m][n], 0, 0, 0);
  }

  // epilogue: +bias, relu, bf16 store
#pragma unroll
  for (int n = 0; n < 4; ++n) {
    int col = nt * 128 + wn * 64 + n * 16 + (lane & 15);
    float bias = b1[e * HDIM + col];
#pragma unroll
    for (int m = 0; m < 4; ++m) {
#pragma unroll
      for (int j = 0; j < 4; ++j) {
        int mr = mt * 128 + wm * 64 + m * 16 + ((lane >> 4) << 2) + j;
        if (mr < cnt) {
          float v = fmaxf(acc[m][n][j] + bias, 0.f);
          hbuf[(size_t)(off + mr) * HDIM + col] = (__bf16)v;
        }
      }
    }
  }
}

// ---------------- GEMM2 (K-split): ybuf[slot,:] += hbuf[slot]·W2bf[e]^T ----------------
__global__ __launch_bounds__(256)
void gemm2_kernel(const __bf16* __restrict__ hbuf, const __bf16* __restrict__ w2bf,
                  const int* __restrict__ ecount, const int* __restrict__ offs,
                  float* __restrict__ ybuf)
{
  const int NTILE = DDIM / 128;   // 8
  const int MTILE = NTOK / 128;   // 16
  int bid = blockIdx.x;
  int e = bid / (MTILE * NTILE * KSPLIT);
  int rem = bid % (MTILE * NTILE * KSPLIT);
  int mt = rem / (NTILE * KSPLIT);
  int rem2 = rem % (NTILE * KSPLIT);
  int nt = rem2 / KSPLIT, kc = rem2 % KSPLIT;
  int cnt = ecount[e];
  if (mt * 128 >= cnt) return;
  int off = offs[e];

  __shared__ __bf16 As[3][128 * 32];
  __shared__ __bf16 Bs[3][128 * 32];

  int tid = threadIdx.x, lane = tid & 63, wave = tid >> 6;
  int wm = wave >> 1, wn = wave & 1;

  const __bf16* aP[2];
  const __bf16* bP[2];
#pragma unroll
  for (int c = 0; c < 2; ++c) {
    int row = c * 64 + (tid >> 2);
    int cd = (tid & 3) ^ ((row >> 1) & 3);
    aP[c] = hbuf + (size_t)(off + mt * 128 + row) * HDIM + cd * 8;
    bP[c] = w2bf + (size_t)e * DDIM * HDIM + (size_t)(nt * 128 + row) * HDIM + cd * 8;
  }
  int cg = ((lane >> 4) ^ ((lane >> 1) & 3)) << 3;

  f32x4 acc[4][4];
#pragma unroll
  for (int m = 0; m < 4; ++m)
#pragma unroll
    for (int n = 0; n < 4; ++n) acc[m][n] = (f32x4){0.f, 0.f, 0.f, 0.f};

  const int KCH = HDIM / KSPLIT;      // 2048
  const int NIT = KCH / 32;           // 64
  int kbeg = kc * KCH;
#pragma unroll
  for (int pt = 0; pt < 2; ++pt)
#pragma unroll
    for (int c = 0; c < 2; ++c) {
      gld16(aP[c] + kbeg + pt * 32, &As[pt][(c * 64 + wave * 16) * 32]);
      gld16(bP[c] + kbeg + pt * 32, &Bs[pt][(c * 64 + wave * 16) * 32]);
    }

  for (int it = 0; it < NIT; ++it) {
    int cur = it % 3;
    if (it + 1 < NIT) asm volatile("s_waitcnt vmcnt(4)" ::: "memory");
    else              asm volatile("s_waitcnt vmcnt(0)" ::: "memory");
    __builtin_amdgcn_s_barrier();
    __builtin_amdgcn_sched_barrier(0);
    if (it + 2 < NIT) {
      int nb = (it + 2) % 3;
      int k0 = kbeg + (it + 2) * 32;
#pragma unroll
      for (int c = 0; c < 2; ++c) {
        gld16(aP[c] + k0, &As[nb][(c * 64 + wave * 16) * 32]);
        gld16(bP[c] + k0, &Bs[nb][(c * 64 + wave * 16) * 32]);
      }
    }
    bf16x8 af[4], bfr[4];
#pragma unroll
    for (int m = 0; m < 4; ++m) af[m]  = *(const bf16x8*)&As[cur][(wm*64 + m*16 + (lane & 15)) * 32 + cg];
#pragma unroll
    for (int n = 0; n < 4; ++n) bfr[n] = *(const bf16x8*)&Bs[cur][(wn*64 + n*16 + (lane & 15)) * 32 + cg];
#pragma unroll
    for (int m = 0; m < 4; ++m)
#pragma unroll
      for (int n = 0; n < 4; ++n)
        acc[m][n] = __builtin_amdgcn_mfma_f32_16x16x32_bf16(af[m], bfr[n], acc[m][n], 0, 0, 0);
  }

  // epilogue: atomic accumulate raw partials (bias+gate weight in combine)
#pragma unroll
  for (int m = 0; m < 4; ++m) {
#pragma unroll
    for (int j = 0; j < 4; ++j) {
      int mr = mt * 128 + wm * 64 + m * 16 + ((lane >> 4) << 2) + j;
      if (mr >= cnt) continue;
      int slot = off + mr;
#pragma unroll
      for (int n = 0; n < 4; ++n) {
        int col = nt * 128 + wn * 64 + n * 16 + (lane & 15);
        atomicAdd(&ybuf[(size_t)slot * DDIM + col], acc[m][n][j]);
      }
    }
  }
}

// ---------------- combine: out[t] = wA*(y[sA]+b2[eA]) + wB*(y[sB]+b2[eB]) ----------------
__global__ __launch_bounds__(256)
void combine_kernel(const float* __restrict__ ybuf, const int* __restrict__ slot_of,
                    const int* __restrict__ tix, const float* __restrict__ twt,
                    const float* __restrict__ b2, float* __restrict__ out)
{
  int t = blockIdx.x;
  int d4 = threadIdx.x;
  int sA = slot_of[2*t], sB = slot_of[2*t + 1];
  f32x4 r = (f32x4){0.f, 0.f, 0.f, 0.f};
  if (sA >= 0) {
    float wA = twt[2*t];
    f32x4 y = ((const f32x4*)(ybuf + (size_t)sA * DDIM))[d4];
    f32x4 b = ((const f32x4*)(b2 + (size_t)tix[2*t] * DDIM))[d4];
    r += wA * (y + b);
  }
  if (sB >= 0) {
    float wB = twt[2*t + 1];
    f32x4 y = ((const f32x4*)(ybuf + (size_t)sB * DDIM))[d4];
    f32x4 b = ((const f32x4*)(b2 + (size_t)tix[2*t + 1] * DDIM))[d4];
    r += wB * (y + b);
  }
  ((f32x4*)(out + (size_t)t * DDIM))[d4] = r;
}

extern "C" void kernel_launch(void* const* d_in, const int* in_sizes, int n_in,
                              void* d_out, int out_size, void* d_ws, size_t ws_size,
                              hipStream_t stream)
{
  const float* x  = (const float*)d_in[0];
  const unsigned char* pm = (const unsigned char*)d_in[1];
  const float* Wg = (const float*)d_in[2];
  const float* W1 = (const float*)d_in[3];
  const float* b1 = (const float*)d_in[4];
  const float* W2 = (const float*)d_in[5];
  const float* b2 = (const float*)d_in[6];
  float* out = (float*)d_out;
  float* gate_out = out + (size_t)NTOK * DDIM;        // 2097152
  float* lb_out = gate_out + (size_t)NTOK * NEXP;     // 2113536

  char* w = (char*)d_ws;
  int*   ecount   = (int*)(w + 0);
  int*   offs     = (int*)(w + 64);
  int*   fill     = (int*)(w + 128);
  int*   tix      = (int*)(w + 512);                       // 16 KB
  float* twt      = (float*)(w + 512 + 16384);             // 16 KB
  int*   tok_list = (int*)(w + 512 + 32768);               // 16 KB
  int*   slot_of  = (int*)(w + 512 + 49152);               // 16 KB
  uintptr_t p = ((uintptr_t)(w + 512 + 65536) + 255) & ~(uintptr_t)255;
  __bf16* xbf  = (__bf16*)p;                                    // 4 MB
  p += (size_t)NTOK * DDIM * 2;
  __bf16* wbf  = (__bf16*)p;                                    // 67 MB (W1bf, then W2bf)
  p += (size_t)NEXP * HDIM * DDIM * 2;
  __bf16* hbuf = (__bf16*)p;                                    // 33 MB
  p += (size_t)(2 * NTOK + 128) * HDIM * 2;
  float*  ybuf = (float*)p;                                     // 16 MB

  init_kernel<<<1, 64, 0, stream>>>(fill);
  conv_kernel<<<2048, 256, 0, stream>>>(W1, wbf, (long)NEXP * HDIM * DDIM / 8);
  zero_y_kernel<<<(2 * NTOK * DDIM / 4) / 256, 256, 0, stream>>>(ybuf);
  gate_kernel<<<NTOK / 4, 256, 0, stream>>>(x, pm, Wg, gate_out, tix, twt, xbf);
  stats_kernel<<<1, 1024, 0, stream>>>(gate_out, tix, pm, ecount, offs, lb_out);
  compact_kernel<<<NTOK / 256, 256, 0, stream>>>(pm, tix, offs, fill, tok_list, slot_of);
  gemm1_kernel<<<NEXP * (NTOK / 128) * (HDIM / 128), 256, 0, stream>>>(xbf, wbf, b1, ecount, offs, tok_list, hbuf);
  conv_kernel<<<2048, 256, 0, stream>>>(W2, wbf, (long)NEXP * DDIM * HDIM / 8);
  gemm2_kernel<<<NEXP * (NTOK / 128) * (DDIM / 128) * KSPLIT, 256, 0, stream>>>(hbuf, wbf, ecount, offs, ybuf);
  combine_kernel<<<NTOK, 256, 0, stream>>>(ybuf, slot_of, tix, twt, b2, out);
}